// Round 2
// baseline (11249.560 us; speedup 1.0000x reference)
//
#include <hip/hip_runtime.h>
#include <math.h>

#define NNODES 5000
#define NEDGES 50000
#define NELG   200000
#define DMODEL 512
#define NH     8
#define NLAYERS 2

// ---- bf16 helpers (stored as unsigned short) ------------------------------
__device__ __forceinline__ float b2f(unsigned short u) {
    union { unsigned int i; float f; } c;
    c.i = ((unsigned int)u) << 16;
    return c.f;
}
__device__ __forceinline__ unsigned short f2b(float f) {
    union { float f; unsigned int i; } c;
    c.f = f;
    unsigned int i = c.i;
    return (unsigned short)((i + 0x7fffu + ((i >> 16) & 1u)) >> 16);
}

// ---------------------------------------------------------------------------
// GEMM: C[M,Nc](bf16) = A[M,K](bf16) @ W[K,Nc](fp32) (+bias fp32) (+add bf16)
// add row = gidx ? gidx[r] : r (residual / gathered add). relu optional.
// K%16==0, Nc%64==0, M guarded.
// ---------------------------------------------------------------------------
__global__ __launch_bounds__(256) void gemm_kernel(
    const unsigned short* __restrict__ A, const float* __restrict__ W,
    const float* __restrict__ bias, const unsigned short* __restrict__ add,
    const int* __restrict__ gidx, unsigned short* __restrict__ C,
    int M, int K, int Nc, int relu)
{
    __shared__ float As[16][68];   // [k][m]
    __shared__ float Bs[16][68];   // [k][n]

    const int tid = threadIdx.x;
    const int tx = tid & 15, ty = tid >> 4;
    const int rowBase = blockIdx.y << 6, colBase = blockIdx.x << 6;

    float acc[4][4] = {};

    const int ar = tid >> 2;            // 0..63
    const int ak = (tid & 3) << 2;      // 0,4,8,12
    const int bk = tid >> 4;            // 0..15
    const int bc = (tid & 15) << 2;     // 0..60
    const int grow = rowBase + ar;
    const unsigned short* Arow = A + (size_t)grow * K;

    for (int k0 = 0; k0 < K; k0 += 16) {
        ushort4 av = make_ushort4(0, 0, 0, 0);
        if (grow < M) av = *(const ushort4*)(Arow + k0 + ak);
        As[ak + 0][ar] = b2f(av.x);
        As[ak + 1][ar] = b2f(av.y);
        As[ak + 2][ar] = b2f(av.z);
        As[ak + 3][ar] = b2f(av.w);
        *(float4*)&Bs[bk][bc] =
            *(const float4*)(W + (size_t)(k0 + bk) * Nc + colBase + bc);
        __syncthreads();
        #pragma unroll
        for (int kk = 0; kk < 16; ++kk) {
            const float4 a4 = *(const float4*)&As[kk][ty << 2];
            const float4 b4 = *(const float4*)&Bs[kk][tx << 2];
            const float aa[4] = {a4.x, a4.y, a4.z, a4.w};
            const float bb[4] = {b4.x, b4.y, b4.z, b4.w};
            #pragma unroll
            for (int i2 = 0; i2 < 4; ++i2)
                #pragma unroll
                for (int j2 = 0; j2 < 4; ++j2)
                    acc[i2][j2] = fmaf(aa[i2], bb[j2], acc[i2][j2]);
        }
        __syncthreads();
    }

    #pragma unroll
    for (int i2 = 0; i2 < 4; ++i2) {
        const int r = rowBase + (ty << 2) + i2;
        if (r >= M) continue;
        const int arow = gidx ? gidx[r] : r;
        const unsigned short* addr = add ? (add + (size_t)arow * Nc) : nullptr;
        unsigned short* crow = C + (size_t)r * Nc;
        #pragma unroll
        for (int j2 = 0; j2 < 4; ++j2) {
            const int c = colBase + (tx << 2) + j2;
            float v = acc[i2][j2];
            if (bias) v += bias[c];
            if (addr) v += b2f(addr[c]);
            if (relu) v = fmaxf(v, 0.0f);
            crow[c] = f2b(v);
        }
    }
}

// ---------------------------------------------------------------------------
// LayerNorm in place over bf16 rows of width 512. One wave per row.
// ---------------------------------------------------------------------------
__global__ __launch_bounds__(256) void ln_kernel(
    unsigned short* __restrict__ x, const float* __restrict__ g,
    const float* __restrict__ b, int M)
{
    const int row = blockIdx.x * 4 + (threadIdx.x >> 6);
    if (row >= M) return;
    const int lane = threadIdx.x & 63;
    unsigned short* xr = x + (size_t)row * DMODEL;

    float vals[8];
    float s = 0.f, s2 = 0.f;
    #pragma unroll
    for (int i = 0; i < 8; ++i) {
        const float v = b2f(xr[lane + i * 64]);
        vals[i] = v; s += v; s2 += v * v;
    }
    #pragma unroll
    for (int o = 32; o > 0; o >>= 1) {
        s  += __shfl_down(s, o);
        s2 += __shfl_down(s2, o);
    }
    s  = __shfl(s, 0);
    s2 = __shfl(s2, 0);
    const float m = s * (1.0f / DMODEL);
    const float var = s2 * (1.0f / DMODEL) - m * m;
    const float r = rsqrtf(var + 1e-5f);
    #pragma unroll
    for (int i = 0; i < 8; ++i) {
        const int c = lane + i * 64;
        xr[c] = f2b((vals[i] - m) * r * g[c] + b[c]);
    }
}

// ---------------------------------------------------------------------------
// Attention scores: one wave per (edge, head). bf16 inputs, fp32 score out.
// ---------------------------------------------------------------------------
__global__ __launch_bounds__(256) void score_kernel(
    const unsigned short* __restrict__ kmat, const unsigned short* __restrict__ qmat,
    const unsigned short* __restrict__ efeat,
    const int* __restrict__ src, const int* __restrict__ dst,
    float* __restrict__ score, int Ne)
{
    const int eh = blockIdx.x * 4 + (threadIdx.x >> 6);
    if (eh >= Ne * NH) return;
    const int e = eh >> 3, h = eh & 7;
    const int lane = threadIdx.x & 63;
    const int s_ = src[e], d_ = dst[e];
    const int col = h * 64 + lane;

    float kv = b2f(kmat[(size_t)s_ * DMODEL + col]);
    if (efeat) kv += b2f(efeat[(size_t)e * DMODEL + col]);
    const float qv = b2f(qmat[(size_t)d_ * DMODEL + col]);
    float p = kv * qv;
    #pragma unroll
    for (int o = 32; o > 0; o >>= 1) p += __shfl_down(p, o);
    if (lane == 0) {
        float sc = p * 0.125f;                       // 1/sqrt(64)
        sc = fminf(fmaxf(sc, -10.0f), 10.0f);
        score[e * NH + h] = expf(sc);
    }
}

// ---------------------------------------------------------------------------
// Segment-sum accumulate (fp32 atomics). One thread per (edge, col).
// ---------------------------------------------------------------------------
__global__ __launch_bounds__(256) void accum_kernel(
    const unsigned short* __restrict__ vmat, const unsigned short* __restrict__ efeat,
    const int* __restrict__ src, const int* __restrict__ dst,
    const float* __restrict__ score,
    float* __restrict__ wv, float* __restrict__ z, int Ne)
{
    const int idx = blockIdx.x * 256 + threadIdx.x;
    if (idx >= Ne * DMODEL) return;
    const int e = idx >> 9;
    const int col = idx & 511;
    const int h = col >> 6;
    const float sc = score[e * NH + h];
    const int s_ = src[e], d_ = dst[e];
    float vv = b2f(vmat[(size_t)s_ * DMODEL + col]);
    if (efeat) vv += b2f(efeat[(size_t)e * DMODEL + col]);
    atomicAdd(&wv[(size_t)d_ * DMODEL + col], vv * sc);
    if ((col & 63) == 0) atomicAdd(&z[d_ * NH + h], sc);
}

// wv(fp32)/z -> bf16 out
__global__ __launch_bounds__(256) void divide_cast_kernel(
    const float* __restrict__ wv, const float* __restrict__ z,
    unsigned short* __restrict__ out, int rows)
{
    const int idx = blockIdx.x * 256 + threadIdx.x;
    if (idx >= rows * DMODEL) return;
    const int seg = idx >> 9;
    const int h = (idx >> 6) & 7;
    out[idx] = f2b(wv[idx] / z[seg * NH + h]);
}

// lg16[e, col] = bf16(rel_embed[edge_feat[e], col])
__global__ __launch_bounds__(256) void gather_rel_kernel(
    const float* __restrict__ rel, const int* __restrict__ ef,
    unsigned short* __restrict__ lg)
{
    const int idx = blockIdx.x * 256 + threadIdx.x;
    if (idx >= NEDGES * DMODEL) return;
    const int e = idx >> 9;
    const int col = idx & 511;
    lg[idx] = f2b(rel[(size_t)ef[e] * DMODEL + col]);
}

__global__ __launch_bounds__(256) void cast_f2b_kernel(
    const float* __restrict__ in, unsigned short* __restrict__ out, int n)
{
    const int idx = blockIdx.x * 256 + threadIdx.x;
    if (idx < n) out[idx] = f2b(in[idx]);
}

__global__ __launch_bounds__(256) void cast_b2f_kernel(
    const unsigned short* __restrict__ in, float* __restrict__ out, int n)
{
    const int idx = blockIdx.x * 256 + threadIdx.x;
    if (idx < n) out[idx] = b2f(in[idx]);
}

__global__ __launch_bounds__(256) void zero_kernel(float4* __restrict__ p, int n4)
{
    const int idx = blockIdx.x * 256 + threadIdx.x;
    if (idx < n4) p[idx] = make_float4(0.f, 0.f, 0.f, 0.f);
}

// ---------------------------------------------------------------------------
static inline void gemm(hipStream_t st, const unsigned short* A, const float* W,
                        const float* bias, const unsigned short* add, const int* gidx,
                        unsigned short* C, int M, int K, int Nc, int relu)
{
    dim3 g(Nc / 64, (M + 63) / 64);
    gemm_kernel<<<g, 256, 0, st>>>(A, W, bias, add, gidx, C, M, K, Nc, relu);
}
static inline void zero(hipStream_t st, void* p, size_t nfloats)
{
    const int n4 = (int)(nfloats / 4);
    zero_kernel<<<(n4 + 255) / 256, 256, 0, st>>>((float4*)p, n4);
}

extern "C" void kernel_launch(void* const* d_in, const int* in_sizes, int n_in,
                              void* d_out, int out_size, void* d_ws, size_t ws_size,
                              hipStream_t stream)
{
    const float* x_in      = (const float*)d_in[0];
    const int*   edge_feat = (const int*)d_in[1];
    const int*   src_ids   = (const int*)d_in[2];
    const int*   dst_ids   = (const int*)d_in[3];
    const int*   lg_src    = (const int*)d_in[4];
    const int*   lg_dst    = (const int*)d_in[5];
    const float* rel_embed = (const float*)d_in[6];

    const float* n_Wq = (const float*)d_in[7];   const float* n_bq = (const float*)d_in[8];
    const float* n_Wk = (const float*)d_in[9];   const float* n_Wv = (const float*)d_in[10];
    const float* n_Wo = (const float*)d_in[11];  const float* n_bo = (const float*)d_in[12];
    const float* n_lg = (const float*)d_in[13];  const float* n_lb = (const float*)d_in[14];
    const float* n_f1 = (const float*)d_in[15];  const float* n_fb1 = (const float*)d_in[16];
    const float* n_f2 = (const float*)d_in[17];  const float* n_fb2 = (const float*)d_in[18];
    const float* n_fg = (const float*)d_in[19];  const float* n_fb = (const float*)d_in[20];

    const float* e_Wq = (const float*)d_in[21];  const float* e_bq = (const float*)d_in[22];
    const float* e_Wk = (const float*)d_in[23];  const float* e_Wv = (const float*)d_in[24];
    const float* e_Wo = (const float*)d_in[25];  const float* e_bo = (const float*)d_in[26];
    const float* e_lg = (const float*)d_in[27];  const float* e_lb = (const float*)d_in[28];
    const float* e_f1 = (const float*)d_in[29];  const float* e_fb1 = (const float*)d_in[30];
    const float* e_f2 = (const float*)d_in[31];  const float* e_fb2 = (const float*)d_in[32];
    const float* e_fg = (const float*)d_in[33];  const float* e_fb = (const float*)d_in[34];

    const int XSZ  = NNODES * DMODEL;    // 2,560,000
    const int LGSZ = NEDGES * DMODEL;    // 25,600,000

    // ---- workspace layout (bytes): total ~120.6 MB -------------------------
    char* ws = (char*)d_ws;
    unsigned short* lg16  = (unsigned short*)(ws);               // 51,200,000 B
    unsigned short* ve16  = (unsigned short*)(ws + 51200000);    // 51,200,000 B
    float*          sbuf  = (float*)(ws + 102400000);            //  6,400,000 B
    float*          ezb   = (float*)(ws + 108800000);            //  1,600,000 B
    unsigned short* xbufA = (unsigned short*)(ws + 110400000);   //  5,120,000 B
    unsigned short* xbufB = (unsigned short*)(ws + 115520000);   //  5,120,000 B

    // ---- d_out used as scratch until the final casts (112.64 MB) -----------
    char* ob = (char*)d_out;
    unsigned short* qe16 = (unsigned short*)(ob);                // 51,200,000 B
    unsigned short* ke16 = (unsigned short*)(ob + 51200000);     // 51,200,000 B
    float*          ewv  = (float*)(ob);                         // 102,400,000 B (aliases qe+ke)
    unsigned short* nq16 = (unsigned short*)(ob);                //  5,120,000 B
    unsigned short* nk16 = (unsigned short*)(ob + 5120000);
    unsigned short* nv16 = (unsigned short*)(ob + 10240000);
    float*          nwv  = (float*)(ob + 15360000);              // 10,240,000 B
    unsigned short* nhid = (unsigned short*)(ob);                // 20,480,000 B (node FFN hidden)

    // init
    cast_f2b_kernel<<<(XSZ + 255) / 256, 256, 0, stream>>>(x_in, xbufA, XSZ);
    gather_rel_kernel<<<(LGSZ + 255) / 256, 256, 0, stream>>>(rel_embed, edge_feat, lg16);

    unsigned short* xc = xbufA;
    unsigned short* xn = xbufB;

    for (int i = 0; i < NLAYERS; ++i) {
        const size_t wo  = (size_t)i * DMODEL * DMODEL;
        const size_t bo_ = (size_t)i * DMODEL;
        const size_t f1o = (size_t)i * DMODEL * 4 * DMODEL;
        const size_t b1o = (size_t)i * 4 * DMODEL;

        // ================= node update (reads xc, lg16) =================
        gemm(stream, xc, n_Wq + wo, n_bq + bo_, nullptr, nullptr, nq16, NNODES, 512, 512, 0);
        gemm(stream, xc, n_Wk + wo, nullptr,    nullptr, nullptr, nk16, NNODES, 512, 512, 0);
        gemm(stream, xc, n_Wv + wo, nullptr,    nullptr, nullptr, nv16, NNODES, 512, 512, 0);

        score_kernel<<<(NEDGES * NH + 3) / 4, 256, 0, stream>>>(
            nk16, nq16, lg16, src_ids, dst_ids, sbuf, NEDGES);

        zero(stream, nwv, (size_t)XSZ);
        zero(stream, ezb, (size_t)NNODES * NH);
        accum_kernel<<<(NEDGES * DMODEL + 255) / 256, 256, 0, stream>>>(
            nv16, lg16, src_ids, dst_ids, sbuf, nwv, ezb, NEDGES);
        divide_cast_kernel<<<(XSZ + 255) / 256, 256, 0, stream>>>(nwv, ezb, nq16, NNODES);

        gemm(stream, nq16, n_Wo + wo, n_bo + bo_, xc, nullptr, xn, NNODES, 512, 512, 0);
        ln_kernel<<<(NNODES + 3) / 4, 256, 0, stream>>>(xn, n_lg + bo_, n_lb + bo_, NNODES);
        gemm(stream, xn, n_f1 + f1o, n_fb1 + b1o, nullptr, nullptr, nhid, NNODES, 512, 2048, 1);
        gemm(stream, nhid, n_f2 + (size_t)i * 4 * DMODEL * DMODEL, n_fb2 + bo_, xn, nullptr, xn,
             NNODES, 2048, 512, 0);
        ln_kernel<<<(NNODES + 3) / 4, 256, 0, stream>>>(xn, n_fg + bo_, n_fb + bo_, NNODES);

        // ================= edge update (reads PRE-update xc) =================
        gemm(stream, lg16, e_Wq + wo, e_bq + bo_, xc, dst_ids, qe16, NEDGES, 512, 512, 0);
        gemm(stream, lg16, e_Wk + wo, nullptr,    xc, src_ids, ke16, NEDGES, 512, 512, 0);
        gemm(stream, lg16, e_Wv + wo, nullptr,    xc, src_ids, ve16, NEDGES, 512, 512, 0);

        score_kernel<<<(NELG * NH + 3) / 4, 256, 0, stream>>>(
            ke16, qe16, nullptr, lg_src, lg_dst, sbuf, NELG);

        zero(stream, ewv, (size_t)LGSZ);
        zero(stream, ezb, (size_t)NEDGES * NH);
        accum_kernel<<<(NELG * DMODEL + 255) / 256, 256, 0, stream>>>(
            ve16, nullptr, lg_src, lg_dst, sbuf, ewv, ezb, NELG);
        divide_cast_kernel<<<(LGSZ + 255) / 256, 256, 0, stream>>>(ewv, ezb, ve16, NEDGES);

        // attn-out + residual, in place over lg16
        gemm(stream, ve16, e_Wo + wo, e_bo + bo_, lg16, nullptr, lg16, NEDGES, 512, 512, 0);
        ln_kernel<<<(NEDGES + 3) / 4, 256, 0, stream>>>(lg16, e_lg + bo_, e_lb + bo_, NEDGES);

        // FFN over edges, 4 chunks of 12500 rows; hidden reuses ve16
        for (int c = 0; c < 4; ++c) {
            unsigned short* y1c = lg16 + (size_t)c * 12500 * DMODEL;
            gemm(stream, y1c, e_f1 + f1o, e_fb1 + b1o, nullptr, nullptr, ve16, 12500, 512, 2048, 1);
            gemm(stream, ve16, e_f2 + (size_t)i * 4 * DMODEL * DMODEL, e_fb2 + bo_, y1c, nullptr,
                 y1c, 12500, 2048, 512, 0);
        }
        ln_kernel<<<(NEDGES + 3) / 4, 256, 0, stream>>>(lg16, e_fg + bo_, e_fb + bo_, NEDGES);

        // swap x buffers
        unsigned short* t = xc; xc = xn; xn = t;
    }

    // final: bf16 (ws) -> fp32 d_out. d_out scratch regions are dead now.
    float* out_f = (float*)d_out;
    cast_b2f_kernel<<<(XSZ + 255) / 256, 256, 0, stream>>>(xc, out_f, XSZ);
    cast_b2f_kernel<<<(LGSZ + 255) / 256, 256, 0, stream>>>(lg16, out_f + XSZ, LGSZ);
}

// Round 3
// 4939.612 us; speedup vs baseline: 2.2774x; 2.2774x over previous
//
#include <hip/hip_runtime.h>
#include <math.h>

#define NNODES 5000
#define NEDGES 50000
#define NELG   200000
#define DMODEL 512
#define NH     8
#define NLAYERS 2

typedef __bf16 bf16x8 __attribute__((ext_vector_type(8)));
typedef float  f32x4  __attribute__((ext_vector_type(4)));

// ---- bf16 helpers (stored as unsigned short) ------------------------------
__device__ __forceinline__ float b2f(unsigned short u) {
    union { unsigned int i; float f; } c;
    c.i = ((unsigned int)u) << 16;
    return c.f;
}
__device__ __forceinline__ unsigned short f2b(float f) {
    union { float f; unsigned int i; } c;
    c.f = f;
    unsigned int i = c.i;
    return (unsigned short)((i + 0x7fffu + ((i >> 16) & 1u)) >> 16);
}

// ---------------------------------------------------------------------------
// MFMA GEMM: C[M,N](bf16) = A[M,K](bf16) @ Bt[N,K](bf16)^T
//            (+bias fp32[N]) (+add bf16 row gidx?gidx[r]:r) (relu?)
// 128x128 tile, BK=32, 4 waves, mfma_f32_16x16x32_bf16.
// K%32==0, N%128==0. M arbitrary (staging rows clamped, stores guarded).
// ---------------------------------------------------------------------------
#define BM 128
#define BN 128
#define BK 32

__global__ __launch_bounds__(256) void mfma_gemm_kernel(
    const unsigned short* __restrict__ A, const unsigned short* __restrict__ Bt,
    const float* __restrict__ bias, const unsigned short* __restrict__ add,
    const int* __restrict__ gidx, unsigned short* __restrict__ C,
    int M, int K, int N, int relu)
{
    __shared__ __align__(16) unsigned short ldsA[BM * BK];  // [m][k] 8 KB
    __shared__ __align__(16) unsigned short ldsB[BN * BK];  // [n][k] 8 KB

    const int tid  = threadIdx.x;
    const int lane = tid & 63;
    const int wave = tid >> 6;
    const int quad = lane >> 4;
    const int l16  = lane & 15;

    const int rowBase = blockIdx.y * BM;
    const int colBase = blockIdx.x * BN;
    const int wm = (wave >> 1) * 64;   // wave's quadrant in the 128x128 tile
    const int wn = (wave & 1) * 64;

    // staging: group g covers LDS bytes [g*16, g*16+16); row=g>>2, kchunk=(g&3)*8
    const int g0 = tid, g1 = tid + 256;
    int ra0 = rowBase + (g0 >> 2); if (ra0 > M - 1) ra0 = M - 1;
    int ra1 = rowBase + (g1 >> 2); if (ra1 > M - 1) ra1 = M - 1;
    const unsigned short* gA0 = A + (size_t)ra0 * K + ((g0 & 3) << 3);
    const unsigned short* gA1 = A + (size_t)ra1 * K + ((g1 & 3) << 3);
    const unsigned short* gB0 = Bt + (size_t)(colBase + (g0 >> 2)) * K + ((g0 & 3) << 3);
    const unsigned short* gB1 = Bt + (size_t)(colBase + (g1 >> 2)) * K + ((g1 & 3) << 3);
    unsigned short* lA0 = ldsA + g0 * 8;
    unsigned short* lA1 = ldsA + g1 * 8;
    unsigned short* lB0 = ldsB + g0 * 8;
    unsigned short* lB1 = ldsB + g1 * 8;

    const f32x4 zv = {0.f, 0.f, 0.f, 0.f};
    f32x4 acc[4][4];
    #pragma unroll
    for (int i = 0; i < 4; ++i)
        #pragma unroll
        for (int j = 0; j < 4; ++j) acc[i][j] = zv;

    for (int k0 = 0; k0 < K; k0 += BK) {
        __builtin_amdgcn_global_load_lds(
            (const __attribute__((address_space(1))) void*)(gA0 + k0),
            (__attribute__((address_space(3))) void*)lA0, 16, 0, 0);
        __builtin_amdgcn_global_load_lds(
            (const __attribute__((address_space(1))) void*)(gA1 + k0),
            (__attribute__((address_space(3))) void*)lA1, 16, 0, 0);
        __builtin_amdgcn_global_load_lds(
            (const __attribute__((address_space(1))) void*)(gB0 + k0),
            (__attribute__((address_space(3))) void*)lB0, 16, 0, 0);
        __builtin_amdgcn_global_load_lds(
            (const __attribute__((address_space(1))) void*)(gB1 + k0),
            (__attribute__((address_space(3))) void*)lB1, 16, 0, 0);
        __syncthreads();   // compiler emits vmcnt(0) drain before s_barrier

        bf16x8 af[4], bfr[4];
        #pragma unroll
        for (int i = 0; i < 4; ++i)
            af[i] = *(const bf16x8*)(ldsA + (wm + i * 16 + l16) * BK + quad * 8);
        #pragma unroll
        for (int j = 0; j < 4; ++j)
            bfr[j] = *(const bf16x8*)(ldsB + (wn + j * 16 + l16) * BK + quad * 8);
        #pragma unroll
        for (int i = 0; i < 4; ++i)
            #pragma unroll
            for (int j = 0; j < 4; ++j)
                acc[i][j] = __builtin_amdgcn_mfma_f32_16x16x32_bf16(
                    af[i], bfr[j], acc[i][j], 0, 0, 0);
        __syncthreads();
    }

    // epilogue: C/D layout col=lane&15, row=quad*4+reg (m89-verified)
    #pragma unroll
    for (int i = 0; i < 4; ++i) {
        #pragma unroll
        for (int r = 0; r < 4; ++r) {
            const int row = rowBase + wm + i * 16 + quad * 4 + r;
            if (row >= M) continue;
            const int arow = gidx ? gidx[row] : row;
            const unsigned short* addr = add ? add + (size_t)arow * N : nullptr;
            unsigned short* crow = C + (size_t)row * N;
            #pragma unroll
            for (int j = 0; j < 4; ++j) {
                const int col = colBase + wn + j * 16 + l16;
                float v = acc[i][j][r];
                if (bias) v += bias[col];
                if (addr) v += b2f(addr[col]);
                if (relu) v = fmaxf(v, 0.0f);
                crow[col] = f2b(v);
            }
        }
    }
}

// ---------------------------------------------------------------------------
// W[K][N] fp32 -> Wt[N][K] bf16 (tiled transpose). K,N % 32 == 0.
// ---------------------------------------------------------------------------
__global__ __launch_bounds__(256) void transpose_cast_kernel(
    const float* __restrict__ W, unsigned short* __restrict__ Wt, int K, int N)
{
    __shared__ float t[32][33];
    const int n0 = blockIdx.x << 5, k0 = blockIdx.y << 5;
    const int tx = threadIdx.x & 31, ty = threadIdx.x >> 5;   // ty: 0..7
    #pragma unroll
    for (int r = 0; r < 32; r += 8)
        t[ty + r][tx] = W[(size_t)(k0 + ty + r) * N + n0 + tx];
    __syncthreads();
    #pragma unroll
    for (int r = 0; r < 32; r += 8)
        Wt[(size_t)(n0 + ty + r) * K + k0 + tx] = f2b(t[tx][ty + r]);
}

// ---------------------------------------------------------------------------
// LayerNorm in place over bf16 rows of width 512. One wave per row.
// ---------------------------------------------------------------------------
__global__ __launch_bounds__(256) void ln_kernel(
    unsigned short* __restrict__ x, const float* __restrict__ g,
    const float* __restrict__ b, int M)
{
    const int row = blockIdx.x * 4 + (threadIdx.x >> 6);
    if (row >= M) return;
    const int lane = threadIdx.x & 63;
    unsigned short* xr = x + (size_t)row * DMODEL;

    float vals[8];
    float s = 0.f, s2 = 0.f;
    #pragma unroll
    for (int i = 0; i < 8; ++i) {
        const float v = b2f(xr[lane + i * 64]);
        vals[i] = v; s += v; s2 += v * v;
    }
    #pragma unroll
    for (int o = 32; o > 0; o >>= 1) {
        s  += __shfl_down(s, o);
        s2 += __shfl_down(s2, o);
    }
    s  = __shfl(s, 0);
    s2 = __shfl(s2, 0);
    const float m = s * (1.0f / DMODEL);
    const float var = s2 * (1.0f / DMODEL) - m * m;
    const float r = rsqrtf(var + 1e-5f);
    #pragma unroll
    for (int i = 0; i < 8; ++i) {
        const int c = lane + i * 64;
        xr[c] = f2b((vals[i] - m) * r * g[c] + b[c]);
    }
}

// ---------------------------------------------------------------------------
// Attention scores: one wave per (edge, head).
// ---------------------------------------------------------------------------
__global__ __launch_bounds__(256) void score_kernel(
    const unsigned short* __restrict__ kmat, const unsigned short* __restrict__ qmat,
    const unsigned short* __restrict__ efeat,
    const int* __restrict__ src, const int* __restrict__ dst,
    float* __restrict__ score, int Ne)
{
    const int eh = blockIdx.x * 4 + (threadIdx.x >> 6);
    if (eh >= Ne * NH) return;
    const int e = eh >> 3, h = eh & 7;
    const int lane = threadIdx.x & 63;
    const int s_ = src[e], d_ = dst[e];
    const int col = h * 64 + lane;

    float kv = b2f(kmat[(size_t)s_ * DMODEL + col]);
    if (efeat) kv += b2f(efeat[(size_t)e * DMODEL + col]);
    const float qv = b2f(qmat[(size_t)d_ * DMODEL + col]);
    float p = kv * qv;
    #pragma unroll
    for (int o = 32; o > 0; o >>= 1) p += __shfl_down(p, o);
    if (lane == 0) {
        float sc = p * 0.125f;                       // 1/sqrt(64)
        sc = fminf(fmaxf(sc, -10.0f), 10.0f);
        score[e * NH + h] = expf(sc);
    }
}

// ---------------------------------------------------------------------------
// Segment-sum accumulate (fp32 atomics). One thread per (edge, col).
// ---------------------------------------------------------------------------
__global__ __launch_bounds__(256) void accum_kernel(
    const unsigned short* __restrict__ vmat, const unsigned short* __restrict__ efeat,
    const int* __restrict__ src, const int* __restrict__ dst,
    const float* __restrict__ score,
    float* __restrict__ wv, float* __restrict__ z, int Ne)
{
    const int idx = blockIdx.x * 256 + threadIdx.x;
    if (idx >= Ne * DMODEL) return;
    const int e = idx >> 9;
    const int col = idx & 511;
    const int h = col >> 6;
    const float sc = score[e * NH + h];
    const int s_ = src[e], d_ = dst[e];
    float vv = b2f(vmat[(size_t)s_ * DMODEL + col]);
    if (efeat) vv += b2f(efeat[(size_t)e * DMODEL + col]);
    atomicAdd(&wv[(size_t)d_ * DMODEL + col], vv * sc);
    if ((col & 63) == 0) atomicAdd(&z[d_ * NH + h], sc);
}

// wv(fp32)/z -> bf16 out
__global__ __launch_bounds__(256) void divide_cast_kernel(
    const float* __restrict__ wv, const float* __restrict__ z,
    unsigned short* __restrict__ out, int rows)
{
    const int idx = blockIdx.x * 256 + threadIdx.x;
    if (idx >= rows * DMODEL) return;
    const int seg = idx >> 9;
    const int h = (idx >> 6) & 7;
    out[idx] = f2b(wv[idx] / z[seg * NH + h]);
}

__global__ __launch_bounds__(256) void gather_rel_kernel(
    const float* __restrict__ rel, const int* __restrict__ ef,
    unsigned short* __restrict__ lg)
{
    const int idx = blockIdx.x * 256 + threadIdx.x;
    if (idx >= NEDGES * DMODEL) return;
    const int e = idx >> 9;
    const int col = idx & 511;
    lg[idx] = f2b(rel[(size_t)ef[e] * DMODEL + col]);
}

__global__ __launch_bounds__(256) void cast_f2b_kernel(
    const float* __restrict__ in, unsigned short* __restrict__ out, int n)
{
    const int idx = blockIdx.x * 256 + threadIdx.x;
    if (idx < n) out[idx] = f2b(in[idx]);
}

__global__ __launch_bounds__(256) void cast_b2f_kernel(
    const unsigned short* __restrict__ in, float* __restrict__ out, int n)
{
    const int idx = blockIdx.x * 256 + threadIdx.x;
    if (idx < n) out[idx] = b2f(in[idx]);
}

__global__ __launch_bounds__(256) void zero_kernel(float4* __restrict__ p, int n4)
{
    const int idx = blockIdx.x * 256 + threadIdx.x;
    if (idx < n4) p[idx] = make_float4(0.f, 0.f, 0.f, 0.f);
}

// ---------------------------------------------------------------------------
static inline void mgemm(hipStream_t st, const unsigned short* A, const unsigned short* Bt,
                         const float* bias, const unsigned short* add, const int* gidx,
                         unsigned short* C, int M, int K, int N, int relu)
{
    dim3 g(N / BN, (M + BM - 1) / BM);
    mfma_gemm_kernel<<<g, 256, 0, st>>>(A, Bt, bias, add, gidx, C, M, K, N, relu);
}
static inline void tcast(hipStream_t st, const float* W, unsigned short* Wt, int K, int N)
{
    dim3 g(N / 32, K / 32);
    transpose_cast_kernel<<<g, 256, 0, st>>>(W, Wt, K, N);
}
static inline void zero(hipStream_t st, void* p, size_t nfloats)
{
    const int n4 = (int)(nfloats / 4);
    zero_kernel<<<(n4 + 255) / 256, 256, 0, st>>>((float4*)p, n4);
}

extern "C" void kernel_launch(void* const* d_in, const int* in_sizes, int n_in,
                              void* d_out, int out_size, void* d_ws, size_t ws_size,
                              hipStream_t stream)
{
    const float* x_in      = (const float*)d_in[0];
    const int*   edge_feat = (const int*)d_in[1];
    const int*   src_ids   = (const int*)d_in[2];
    const int*   dst_ids   = (const int*)d_in[3];
    const int*   lg_src    = (const int*)d_in[4];
    const int*   lg_dst    = (const int*)d_in[5];
    const float* rel_embed = (const float*)d_in[6];

    const float* n_Wq = (const float*)d_in[7];   const float* n_bq = (const float*)d_in[8];
    const float* n_Wk = (const float*)d_in[9];   const float* n_Wv = (const float*)d_in[10];
    const float* n_Wo = (const float*)d_in[11];  const float* n_bo = (const float*)d_in[12];
    const float* n_lg = (const float*)d_in[13];  const float* n_lb = (const float*)d_in[14];
    const float* n_f1 = (const float*)d_in[15];  const float* n_fb1 = (const float*)d_in[16];
    const float* n_f2 = (const float*)d_in[17];  const float* n_fb2 = (const float*)d_in[18];
    const float* n_fg = (const float*)d_in[19];  const float* n_fb = (const float*)d_in[20];

    const float* e_Wq = (const float*)d_in[21];  const float* e_bq = (const float*)d_in[22];
    const float* e_Wk = (const float*)d_in[23];  const float* e_Wv = (const float*)d_in[24];
    const float* e_Wo = (const float*)d_in[25];  const float* e_bo = (const float*)d_in[26];
    const float* e_lg = (const float*)d_in[27];  const float* e_lb = (const float*)d_in[28];
    const float* e_f1 = (const float*)d_in[29];  const float* e_fb1 = (const float*)d_in[30];
    const float* e_f2 = (const float*)d_in[31];  const float* e_fb2 = (const float*)d_in[32];
    const float* e_fg = (const float*)d_in[33];  const float* e_fb = (const float*)d_in[34];

    const int XSZ  = NNODES * DMODEL;    // 2,560,000
    const int LGSZ = NEDGES * DMODEL;    // 25,600,000

    // ---- workspace layout (bytes): ~120.6 MB (proven size) -----------------
    char* ws = (char*)d_ws;
    unsigned short* lg16  = (unsigned short*)(ws);               // 51,200,000 B
    unsigned short* ve16  = (unsigned short*)(ws + 51200000);    // 51,200,000 B (V / hidden)
    float*          sbuf  = (float*)(ws + 102400000);            //  6,400,000 B
    float*          ezb   = (float*)(ws + 108800000);            //  1,600,000 B
    unsigned short* xbufA = (unsigned short*)(ws + 110400000);   //  5,120,000 B
    unsigned short* xbufB = (unsigned short*)(ws + 115520000);   //  5,120,000 B

    // ---- d_out used as scratch until the final casts (112.64 MB total) -----
    char* ob = (char*)d_out;
    unsigned short* qe16 = (unsigned short*)(ob);                // 51,200,000 B
    unsigned short* ke16 = (unsigned short*)(ob + 51200000);     // 51,200,000 B
    float*          ewv  = (float*)(ob);                         // 102,400,000 B (aliases qe+ke)
    unsigned short* nq16 = (unsigned short*)(ob);                //  5,120,000 B
    unsigned short* nk16 = (unsigned short*)(ob + 5120000);
    unsigned short* nv16 = (unsigned short*)(ob + 10240000);
    float*          nwv  = (float*)(ob + 15360000);              // 10,240,000 B
    unsigned short* nhid = (unsigned short*)(ob);                // 20,480,000 B (dead nq/nk/nv/nwv)
    // bf16 transposed-weight slots in the spare tail [102.4 MB, 112.64 MB)
    unsigned short* wtq  = (unsigned short*)(ob + 102400000);    //   524,288 B
    unsigned short* wtk  = (unsigned short*)(ob + 102924288);
    unsigned short* wtv  = (unsigned short*)(ob + 103448576);
    unsigned short* wto  = (unsigned short*)(ob + 103972864);
    unsigned short* wtf1 = (unsigned short*)(ob + 104497152);    // 2,097,152 B
    unsigned short* wtf2 = (unsigned short*)(ob + 106594304);    // 2,097,152 B (ends 108.7 MB)

    // init
    cast_f2b_kernel<<<(XSZ + 255) / 256, 256, 0, stream>>>(x_in, xbufA, XSZ);
    gather_rel_kernel<<<(LGSZ + 255) / 256, 256, 0, stream>>>(rel_embed, edge_feat, lg16);

    unsigned short* xc = xbufA;
    unsigned short* xn = xbufB;

    for (int i = 0; i < NLAYERS; ++i) {
        const size_t wo  = (size_t)i * DMODEL * DMODEL;
        const size_t bo_ = (size_t)i * DMODEL;
        const size_t f1o = (size_t)i * DMODEL * 4 * DMODEL;
        const size_t b1o = (size_t)i * 4 * DMODEL;
        const size_t f2o = (size_t)i * 4 * DMODEL * DMODEL;

        // ================= node update (reads xc, lg16) =================
        tcast(stream, n_Wq + wo, wtq, 512, 512);
        tcast(stream, n_Wk + wo, wtk, 512, 512);
        tcast(stream, n_Wv + wo, wtv, 512, 512);
        tcast(stream, n_Wo + wo, wto, 512, 512);
        tcast(stream, n_f1 + f1o, wtf1, 512, 2048);
        tcast(stream, n_f2 + f2o, wtf2, 2048, 512);

        mgemm(stream, xc, wtq, n_bq + bo_, nullptr, nullptr, nq16, NNODES, 512, 512, 0);
        mgemm(stream, xc, wtk, nullptr,    nullptr, nullptr, nk16, NNODES, 512, 512, 0);
        mgemm(stream, xc, wtv, nullptr,    nullptr, nullptr, nv16, NNODES, 512, 512, 0);

        score_kernel<<<(NEDGES * NH + 3) / 4, 256, 0, stream>>>(
            nk16, nq16, lg16, src_ids, dst_ids, sbuf, NEDGES);

        zero(stream, nwv, (size_t)XSZ);
        zero(stream, ezb, (size_t)NNODES * NH);
        accum_kernel<<<(NEDGES * DMODEL + 255) / 256, 256, 0, stream>>>(
            nv16, lg16, src_ids, dst_ids, sbuf, nwv, ezb, NEDGES);
        divide_cast_kernel<<<(XSZ + 255) / 256, 256, 0, stream>>>(nwv, ezb, nq16, NNODES);

        mgemm(stream, nq16, wto, n_bo + bo_, xc, nullptr, xn, NNODES, 512, 512, 0);
        ln_kernel<<<(NNODES + 3) / 4, 256, 0, stream>>>(xn, n_lg + bo_, n_lb + bo_, NNODES);
        mgemm(stream, xn, wtf1, n_fb1 + b1o, nullptr, nullptr, nhid, NNODES, 512, 2048, 1);
        mgemm(stream, nhid, wtf2, n_fb2 + bo_, xn, nullptr, xn, NNODES, 2048, 512, 0);
        ln_kernel<<<(NNODES + 3) / 4, 256, 0, stream>>>(xn, n_fg + bo_, n_fb + bo_, NNODES);

        // ================= edge update (reads PRE-update xc) =================
        tcast(stream, e_Wq + wo, wtq, 512, 512);
        tcast(stream, e_Wk + wo, wtk, 512, 512);
        tcast(stream, e_Wv + wo, wtv, 512, 512);
        tcast(stream, e_Wo + wo, wto, 512, 512);

        mgemm(stream, lg16, wtq, e_bq + bo_, xc, dst_ids, qe16, NEDGES, 512, 512, 0);
        mgemm(stream, lg16, wtk, nullptr,    xc, src_ids, ke16, NEDGES, 512, 512, 0);
        mgemm(stream, lg16, wtv, nullptr,    xc, src_ids, ve16, NEDGES, 512, 512, 0);

        score_kernel<<<(NELG * NH + 3) / 4, 256, 0, stream>>>(
            ke16, qe16, nullptr, lg_src, lg_dst, sbuf, NELG);

        zero(stream, ewv, (size_t)LGSZ);
        zero(stream, ezb, (size_t)NEDGES * NH);
        accum_kernel<<<(NELG * DMODEL + 255) / 256, 256, 0, stream>>>(
            ve16, nullptr, lg_src, lg_dst, sbuf, ewv, ezb, NELG);
        divide_cast_kernel<<<(LGSZ + 255) / 256, 256, 0, stream>>>(ewv, ezb, ve16, NEDGES);

        // attn-out + residual, in place over lg16 (same-thread read-then-write)
        mgemm(stream, ve16, wto, e_bo + bo_, lg16, nullptr, lg16, NEDGES, 512, 512, 0);
        ln_kernel<<<(NEDGES + 3) / 4, 256, 0, stream>>>(lg16, e_lg + bo_, e_lb + bo_, NEDGES);

        tcast(stream, e_f1 + f1o, wtf1, 512, 2048);
        tcast(stream, e_f2 + f2o, wtf2, 2048, 512);
        // FFN over edges, 4 chunks of 12500 rows; hidden reuses ve16
        for (int c = 0; c < 4; ++c) {
            unsigned short* y1c = lg16 + (size_t)c * 12500 * DMODEL;
            mgemm(stream, y1c, wtf1, e_fb1 + b1o, nullptr, nullptr, ve16, 12500, 512, 2048, 1);
            mgemm(stream, ve16, wtf2, e_fb2 + bo_, y1c, nullptr, y1c, 12500, 2048, 512, 0);
        }
        ln_kernel<<<(NEDGES + 3) / 4, 256, 0, stream>>>(lg16, e_fg + bo_, e_fb + bo_, NEDGES);

        unsigned short* t = xc; xc = xn; xn = t;
    }

    // final: bf16 -> fp32 d_out (all d_out scratch dead now)
    float* out_f = (float*)d_out;
    cast_b2f_kernel<<<(XSZ + 255) / 256, 256, 0, stream>>>(xc, out_f, XSZ);
    cast_b2f_kernel<<<(LGSZ + 255) / 256, 256, 0, stream>>>(lg16, out_f + XSZ, LGSZ);
}

// Round 4
// 3432.381 us; speedup vs baseline: 3.2775x; 1.4391x over previous
//
#include <hip/hip_runtime.h>
#include <math.h>

#define NNODES 5000
#define NEDGES 50000
#define NELG   200000
#define DMODEL 512
#define NH     8
#define NLAYERS 2

typedef __bf16 bf16x8 __attribute__((ext_vector_type(8)));
typedef float  f32x4  __attribute__((ext_vector_type(4)));

// ---- bf16 helpers (stored as unsigned short) ------------------------------
__device__ __forceinline__ float b2f(unsigned short u) {
    union { unsigned int i; float f; } c;
    c.i = ((unsigned int)u) << 16;
    return c.f;
}
__device__ __forceinline__ unsigned short f2b(float f) {
    union { float f; unsigned int i; } c;
    c.f = f;
    unsigned int i = c.i;
    return (unsigned short)((i + 0x7fffu + ((i >> 16) & 1u)) >> 16);
}

// ---------------------------------------------------------------------------
// MFMA GEMM: C[M,N](bf16) = A[M,K](bf16) @ Bt[N,K](bf16)^T
//            (+bias fp32[N]) (+add bf16 row gidx?gidx[r]:r) (relu?)
// ---------------------------------------------------------------------------
#define BM 128
#define BN 128
#define BK 32

__global__ __launch_bounds__(256) void mfma_gemm_kernel(
    const unsigned short* __restrict__ A, const unsigned short* __restrict__ Bt,
    const float* __restrict__ bias, const unsigned short* __restrict__ add,
    const int* __restrict__ gidx, unsigned short* __restrict__ C,
    int M, int K, int N, int relu)
{
    __shared__ __align__(16) unsigned short ldsA[BM * BK];  // [m][k] 8 KB
    __shared__ __align__(16) unsigned short ldsB[BN * BK];  // [n][k] 8 KB

    const int tid  = threadIdx.x;
    const int lane = tid & 63;
    const int wave = tid >> 6;
    const int quad = lane >> 4;
    const int l16  = lane & 15;

    const int rowBase = blockIdx.y * BM;
    const int colBase = blockIdx.x * BN;
    const int wm = (wave >> 1) * 64;
    const int wn = (wave & 1) * 64;

    const int g0 = tid, g1 = tid + 256;
    int ra0 = rowBase + (g0 >> 2); if (ra0 > M - 1) ra0 = M - 1;
    int ra1 = rowBase + (g1 >> 2); if (ra1 > M - 1) ra1 = M - 1;
    const unsigned short* gA0 = A + (size_t)ra0 * K + ((g0 & 3) << 3);
    const unsigned short* gA1 = A + (size_t)ra1 * K + ((g1 & 3) << 3);
    const unsigned short* gB0 = Bt + (size_t)(colBase + (g0 >> 2)) * K + ((g0 & 3) << 3);
    const unsigned short* gB1 = Bt + (size_t)(colBase + (g1 >> 2)) * K + ((g1 & 3) << 3);
    unsigned short* lA0 = ldsA + g0 * 8;
    unsigned short* lA1 = ldsA + g1 * 8;
    unsigned short* lB0 = ldsB + g0 * 8;
    unsigned short* lB1 = ldsB + g1 * 8;

    const f32x4 zv = {0.f, 0.f, 0.f, 0.f};
    f32x4 acc[4][4];
    #pragma unroll
    for (int i = 0; i < 4; ++i)
        #pragma unroll
        for (int j = 0; j < 4; ++j) acc[i][j] = zv;

    for (int k0 = 0; k0 < K; k0 += BK) {
        __builtin_amdgcn_global_load_lds(
            (const __attribute__((address_space(1))) void*)(gA0 + k0),
            (__attribute__((address_space(3))) void*)lA0, 16, 0, 0);
        __builtin_amdgcn_global_load_lds(
            (const __attribute__((address_space(1))) void*)(gA1 + k0),
            (__attribute__((address_space(3))) void*)lA1, 16, 0, 0);
        __builtin_amdgcn_global_load_lds(
            (const __attribute__((address_space(1))) void*)(gB0 + k0),
            (__attribute__((address_space(3))) void*)lB0, 16, 0, 0);
        __builtin_amdgcn_global_load_lds(
            (const __attribute__((address_space(1))) void*)(gB1 + k0),
            (__attribute__((address_space(3))) void*)lB1, 16, 0, 0);
        __syncthreads();

        bf16x8 af[4], bfr[4];
        #pragma unroll
        for (int i = 0; i < 4; ++i)
            af[i] = *(const bf16x8*)(ldsA + (wm + i * 16 + l16) * BK + quad * 8);
        #pragma unroll
        for (int j = 0; j < 4; ++j)
            bfr[j] = *(const bf16x8*)(ldsB + (wn + j * 16 + l16) * BK + quad * 8);
        #pragma unroll
        for (int i = 0; i < 4; ++i)
            #pragma unroll
            for (int j = 0; j < 4; ++j)
                acc[i][j] = __builtin_amdgcn_mfma_f32_16x16x32_bf16(
                    af[i], bfr[j], acc[i][j], 0, 0, 0);
        __syncthreads();
    }

    #pragma unroll
    for (int i = 0; i < 4; ++i) {
        #pragma unroll
        for (int r = 0; r < 4; ++r) {
            const int row = rowBase + wm + i * 16 + quad * 4 + r;
            if (row >= M) continue;
            const int arow = gidx ? gidx[row] : row;
            const unsigned short* addr = add ? add + (size_t)arow * N : nullptr;
            unsigned short* crow = C + (size_t)row * N;
            #pragma unroll
            for (int j = 0; j < 4; ++j) {
                const int col = colBase + wn + j * 16 + l16;
                float v = acc[i][j][r];
                if (bias) v += bias[col];
                if (addr) v += b2f(addr[col]);
                if (relu) v = fmaxf(v, 0.0f);
                crow[col] = f2b(v);
            }
        }
    }
}

// ---------------------------------------------------------------------------
// W[K][N] fp32 -> Wt[N][K] bf16
// ---------------------------------------------------------------------------
__global__ __launch_bounds__(256) void transpose_cast_kernel(
    const float* __restrict__ W, unsigned short* __restrict__ Wt, int K, int N)
{
    __shared__ float t[32][33];
    const int n0 = blockIdx.x << 5, k0 = blockIdx.y << 5;
    const int tx = threadIdx.x & 31, ty = threadIdx.x >> 5;
    #pragma unroll
    for (int r = 0; r < 32; r += 8)
        t[ty + r][tx] = W[(size_t)(k0 + ty + r) * N + n0 + tx];
    __syncthreads();
    #pragma unroll
    for (int r = 0; r < 32; r += 8)
        Wt[(size_t)(n0 + ty + r) * K + k0 + tx] = f2b(t[tx][ty + r]);
}

// ---------------------------------------------------------------------------
// LayerNorm in place over bf16 rows of width 512. One wave per row.
// ---------------------------------------------------------------------------
__global__ __launch_bounds__(256) void ln_kernel(
    unsigned short* __restrict__ x, const float* __restrict__ g,
    const float* __restrict__ b, int M)
{
    const int row = blockIdx.x * 4 + (threadIdx.x >> 6);
    if (row >= M) return;
    const int lane = threadIdx.x & 63;
    unsigned short* xr = x + (size_t)row * DMODEL;

    float vals[8];
    float s = 0.f, s2 = 0.f;
    #pragma unroll
    for (int i = 0; i < 8; ++i) {
        const float v = b2f(xr[lane + i * 64]);
        vals[i] = v; s += v; s2 += v * v;
    }
    #pragma unroll
    for (int o = 32; o > 0; o >>= 1) {
        s  += __shfl_down(s, o);
        s2 += __shfl_down(s2, o);
    }
    s  = __shfl(s, 0);
    s2 = __shfl(s2, 0);
    const float m = s * (1.0f / DMODEL);
    const float var = s2 * (1.0f / DMODEL) - m * m;
    const float r = rsqrtf(var + 1e-5f);
    #pragma unroll
    for (int i = 0; i < 8; ++i) {
        const int c = lane + i * 64;
        xr[c] = f2b((vals[i] - m) * r * g[c] + b[c]);
    }
}

// ---------------------------------------------------------------------------
// CSR build: histogram -> single-block scan -> scatter
// ---------------------------------------------------------------------------
__global__ __launch_bounds__(256) void hist_kernel(
    const int* __restrict__ dst, int* __restrict__ cnt, int ne)
{
    const int j = blockIdx.x * 256 + threadIdx.x;
    if (j < ne) atomicAdd(&cnt[dst[j]], 1);
}

// exclusive scan of cnt[0..n) -> off[0..n]; cur[i]=off[i]. cnt may alias cur.
__global__ __launch_bounds__(1024) void scan_kernel(
    const int* __restrict__ cnt, int* __restrict__ off,
    int* __restrict__ cur, int n)
{
    __shared__ int part[1024];
    const int t = threadIdx.x;
    const int chunk = (n + 1023) >> 10;
    const int lo = t * chunk;
    int hi = lo + chunk; if (hi > n) hi = n;
    int s = 0;
    for (int i = lo; i < hi; ++i) s += cnt[i];
    part[t] = s;
    __syncthreads();
    #pragma unroll
    for (int o = 1; o < 1024; o <<= 1) {
        int v = (t >= o) ? part[t - o] : 0;
        __syncthreads();
        part[t] += v;
        __syncthreads();
    }
    int base = (t == 0) ? 0 : part[t - 1];
    const int total = part[1023];
    for (int i = lo; i < hi; ++i) {
        const int c = cnt[i];          // read before aliased write
        off[i] = base; cur[i] = base;
        base += c;
    }
    if (t == 1023) off[n] = total;
}

__global__ __launch_bounds__(256) void scatter_kernel(
    const int* __restrict__ dst, int* __restrict__ cur,
    int* __restrict__ idx, int ne)
{
    const int j = blockIdx.x * 256 + threadIdx.x;
    if (j < ne) {
        const int p = atomicAdd(&cur[dst[j]], 1);
        idx[p] = j;
    }
}

// ---------------------------------------------------------------------------
// Fused CSR attention. One block (256 thr) per destination segment.
// q[seg,512] bf16: input q row, OVERWRITTEN with attention output (safe:
// each row is read only by its own block, written after all reads).
// ks = k[src[e]] (+efeat[e]); vs = v[src[e]] (+efeat[e]).
// score = exp(clip(dot_head(ks,q)/8, -10, 10)); out = sum(score*vs)/sum(score)
// Thread t handles cols 2t,2t+1; head = t>>5 spans 32 threads (half-wave).
// ---------------------------------------------------------------------------
__global__ __launch_bounds__(256) void attend_kernel(
    unsigned short* __restrict__ q,
    const unsigned short* __restrict__ k,
    const unsigned short* __restrict__ v,
    const unsigned short* __restrict__ efeat,
    const int* __restrict__ src,
    const int* __restrict__ off, const int* __restrict__ idx,
    int nseg)
{
    const int seg = blockIdx.x;
    if (seg >= nseg) return;
    const int t = threadIdx.x;
    const int lane = t & 63;
    const int c0 = t * 2;
    unsigned short* qrow = q + (size_t)seg * DMODEL;
    const ushort2 q2 = *(const ushort2*)(qrow + c0);
    const float qv0 = b2f(q2.x), qv1 = b2f(q2.y);

    float acc0 = 0.f, acc1 = 0.f, zsum = 0.f;
    const int lo = off[seg], hi = off[seg + 1];
    for (int j = lo; j < hi; ++j) {
        const int e = idx[j];
        const int s = src[e];
        const ushort2 k2 = *(const ushort2*)(k + (size_t)s * DMODEL + c0);
        const ushort2 v2 = *(const ushort2*)(v + (size_t)s * DMODEL + c0);
        float kv0 = b2f(k2.x), kv1 = b2f(k2.y);
        float vv0 = b2f(v2.x), vv1 = b2f(v2.y);
        if (efeat) {
            const ushort2 e2 = *(const ushort2*)(efeat + (size_t)e * DMODEL + c0);
            const float e0 = b2f(e2.x), e1 = b2f(e2.y);
            kv0 += e0; kv1 += e1; vv0 += e0; vv1 += e1;
        }
        float p = kv0 * qv0 + kv1 * qv1;
        #pragma unroll
        for (int o = 16; o > 0; o >>= 1) p += __shfl_down(p, o, 32);
        p = __shfl(p, lane & 32);            // broadcast head-sum to half-wave
        float sc = p * 0.125f;               // 1/sqrt(64)
        sc = fminf(fmaxf(sc, -10.0f), 10.0f);
        sc = __expf(sc);
        zsum += sc;
        acc0 = fmaf(sc, vv0, acc0);
        acc1 = fmaf(sc, vv1, acc1);
    }
    const float rz = 1.0f / zsum;
    ushort2 o2;
    o2.x = f2b(acc0 * rz);
    o2.y = f2b(acc1 * rz);
    *(ushort2*)(qrow + c0) = o2;
}

// ---------------------------------------------------------------------------
__global__ __launch_bounds__(256) void gather_rel_kernel(
    const float* __restrict__ rel, const int* __restrict__ ef,
    unsigned short* __restrict__ lg)
{
    const int idx = blockIdx.x * 256 + threadIdx.x;
    if (idx >= NEDGES * DMODEL) return;
    const int e = idx >> 9;
    const int col = idx & 511;
    lg[idx] = f2b(rel[(size_t)ef[e] * DMODEL + col]);
}

__global__ __launch_bounds__(256) void cast_f2b_kernel(
    const float* __restrict__ in, unsigned short* __restrict__ out, int n)
{
    const int idx = blockIdx.x * 256 + threadIdx.x;
    if (idx < n) out[idx] = f2b(in[idx]);
}

__global__ __launch_bounds__(256) void cast_b2f_kernel(
    const unsigned short* __restrict__ in, float* __restrict__ out, int n)
{
    const int idx = blockIdx.x * 256 + threadIdx.x;
    if (idx < n) out[idx] = b2f(in[idx]);
}

__global__ __launch_bounds__(256) void zero_kernel(float4* __restrict__ p, int n4)
{
    const int idx = blockIdx.x * 256 + threadIdx.x;
    if (idx < n4) p[idx] = make_float4(0.f, 0.f, 0.f, 0.f);
}

// ---------------------------------------------------------------------------
static inline void mgemm(hipStream_t st, const unsigned short* A, const unsigned short* Bt,
                         const float* bias, const unsigned short* add, const int* gidx,
                         unsigned short* C, int M, int K, int N, int relu)
{
    dim3 g(N / BN, (M + BM - 1) / BM);
    mfma_gemm_kernel<<<g, 256, 0, st>>>(A, Bt, bias, add, gidx, C, M, K, N, relu);
}
static inline void tcast(hipStream_t st, const float* W, unsigned short* Wt, int K, int N)
{
    dim3 g(N / 32, K / 32);
    transpose_cast_kernel<<<g, 256, 0, st>>>(W, Wt, K, N);
}
static inline void zero(hipStream_t st, void* p, size_t nfloats)
{
    const int n4 = (int)(nfloats / 4);
    zero_kernel<<<(n4 + 255) / 256, 256, 0, st>>>((float4*)p, n4);
}

extern "C" void kernel_launch(void* const* d_in, const int* in_sizes, int n_in,
                              void* d_out, int out_size, void* d_ws, size_t ws_size,
                              hipStream_t stream)
{
    const float* x_in      = (const float*)d_in[0];
    const int*   edge_feat = (const int*)d_in[1];
    const int*   src_ids   = (const int*)d_in[2];
    const int*   dst_ids   = (const int*)d_in[3];
    const int*   lg_src    = (const int*)d_in[4];
    const int*   lg_dst    = (const int*)d_in[5];
    const float* rel_embed = (const float*)d_in[6];

    const float* n_Wq = (const float*)d_in[7];   const float* n_bq = (const float*)d_in[8];
    const float* n_Wk = (const float*)d_in[9];   const float* n_Wv = (const float*)d_in[10];
    const float* n_Wo = (const float*)d_in[11];  const float* n_bo = (const float*)d_in[12];
    const float* n_lg = (const float*)d_in[13];  const float* n_lb = (const float*)d_in[14];
    const float* n_f1 = (const float*)d_in[15];  const float* n_fb1 = (const float*)d_in[16];
    const float* n_f2 = (const float*)d_in[17];  const float* n_fb2 = (const float*)d_in[18];
    const float* n_fg = (const float*)d_in[19];  const float* n_fb = (const float*)d_in[20];

    const float* e_Wq = (const float*)d_in[21];  const float* e_bq = (const float*)d_in[22];
    const float* e_Wk = (const float*)d_in[23];  const float* e_Wv = (const float*)d_in[24];
    const float* e_Wo = (const float*)d_in[25];  const float* e_bo = (const float*)d_in[26];
    const float* e_lg = (const float*)d_in[27];  const float* e_lb = (const float*)d_in[28];
    const float* e_f1 = (const float*)d_in[29];  const float* e_fb1 = (const float*)d_in[30];
    const float* e_f2 = (const float*)d_in[31];  const float* e_fb2 = (const float*)d_in[32];
    const float* e_fg = (const float*)d_in[33];  const float* e_fb = (const float*)d_in[34];

    const int XSZ  = NNODES * DMODEL;
    const int LGSZ = NEDGES * DMODEL;

    // ---- workspace layout ---------------------------------------------------
    char* ws = (char*)d_ws;
    unsigned short* lg16  = (unsigned short*)(ws);               // 51,200,000 B
    unsigned short* ve16  = (unsigned short*)(ws + 51200000);    // 51,200,000 B
    // CSR region (where sbuf/ezb were):
    int* n_off = (int*)(ws + 102400000);                         // 20,480 B
    int* n_cur = (int*)(ws + 102420480);                         // 20,480 B (doubles as cnt)
    int* n_idx = (int*)(ws + 102440960);                         // 200,704 B
    int* e_off = (int*)(ws + 102641664);                         // 200,704 B
    int* e_cur = (int*)(ws + 102842368);                         // 200,704 B (doubles as cnt)
    int* e_idx = (int*)(ws + 103043072);                         // 800,000 B (ends 103.84 MB)
    unsigned short* xbufA = (unsigned short*)(ws + 110400000);   // 5,120,000 B
    unsigned short* xbufB = (unsigned short*)(ws + 115520000);   // 5,120,000 B

    // ---- d_out scratch (112.64 MB) -----------------------------------------
    char* ob = (char*)d_out;
    unsigned short* qe16 = (unsigned short*)(ob);                // 51.2 MB (edge q / attn out)
    unsigned short* ke16 = (unsigned short*)(ob + 51200000);     // 51.2 MB
    unsigned short* nq16 = (unsigned short*)(ob);                // node q / attn out
    unsigned short* nk16 = (unsigned short*)(ob + 5120000);
    unsigned short* nv16 = (unsigned short*)(ob + 10240000);
    unsigned short* nhid = (unsigned short*)(ob);                // 20.48 MB (node FFN hidden)
    unsigned short* wtq  = (unsigned short*)(ob + 102400000);
    unsigned short* wtk  = (unsigned short*)(ob + 102924288);
    unsigned short* wtv  = (unsigned short*)(ob + 103448576);
    unsigned short* wto  = (unsigned short*)(ob + 103972864);
    unsigned short* wtf1 = (unsigned short*)(ob + 104497152);    // 2 MB
    unsigned short* wtf2 = (unsigned short*)(ob + 106594304);    // 2 MB (ends 108.7 MB)

    // ---- init + CSR build (once; indices layer-invariant) ------------------
    cast_f2b_kernel<<<(XSZ + 255) / 256, 256, 0, stream>>>(x_in, xbufA, XSZ);
    gather_rel_kernel<<<(LGSZ + 255) / 256, 256, 0, stream>>>(rel_embed, edge_feat, lg16);

    zero(stream, n_cur, NNODES);
    zero(stream, e_cur, NEDGES);
    hist_kernel<<<(NEDGES + 255) / 256, 256, 0, stream>>>(dst_ids, n_cur, NEDGES);
    hist_kernel<<<(NELG + 255) / 256, 256, 0, stream>>>(lg_dst, e_cur, NELG);
    scan_kernel<<<1, 1024, 0, stream>>>(n_cur, n_off, n_cur, NNODES);
    scan_kernel<<<1, 1024, 0, stream>>>(e_cur, e_off, e_cur, NEDGES);
    scatter_kernel<<<(NEDGES + 255) / 256, 256, 0, stream>>>(dst_ids, n_cur, n_idx, NEDGES);
    scatter_kernel<<<(NELG + 255) / 256, 256, 0, stream>>>(lg_dst, e_cur, e_idx, NELG);

    unsigned short* xc = xbufA;
    unsigned short* xn = xbufB;

    for (int i = 0; i < NLAYERS; ++i) {
        const size_t wo  = (size_t)i * DMODEL * DMODEL;
        const size_t bo_ = (size_t)i * DMODEL;
        const size_t f1o = (size_t)i * DMODEL * 4 * DMODEL;
        const size_t b1o = (size_t)i * 4 * DMODEL;
        const size_t f2o = (size_t)i * 4 * DMODEL * DMODEL;

        // ================= node update (reads xc, lg16) =================
        tcast(stream, n_Wq + wo, wtq, 512, 512);
        tcast(stream, n_Wk + wo, wtk, 512, 512);
        tcast(stream, n_Wv + wo, wtv, 512, 512);
        tcast(stream, n_Wo + wo, wto, 512, 512);
        tcast(stream, n_f1 + f1o, wtf1, 512, 2048);
        tcast(stream, n_f2 + f2o, wtf2, 2048, 512);

        mgemm(stream, xc, wtq, n_bq + bo_, nullptr, nullptr, nq16, NNODES, 512, 512, 0);
        mgemm(stream, xc, wtk, nullptr,    nullptr, nullptr, nk16, NNODES, 512, 512, 0);
        mgemm(stream, xc, wtv, nullptr,    nullptr, nullptr, nv16, NNODES, 512, 512, 0);

        attend_kernel<<<NNODES, 256, 0, stream>>>(
            nq16, nk16, nv16, lg16, src_ids, n_off, n_idx, NNODES);

        mgemm(stream, nq16, wto, n_bo + bo_, xc, nullptr, xn, NNODES, 512, 512, 0);
        ln_kernel<<<(NNODES + 3) / 4, 256, 0, stream>>>(xn, n_lg + bo_, n_lb + bo_, NNODES);
        mgemm(stream, xn, wtf1, n_fb1 + b1o, nullptr, nullptr, nhid, NNODES, 512, 2048, 1);
        mgemm(stream, nhid, wtf2, n_fb2 + bo_, xn, nullptr, xn, NNODES, 2048, 512, 0);
        ln_kernel<<<(NNODES + 3) / 4, 256, 0, stream>>>(xn, n_fg + bo_, n_fb + bo_, NNODES);

        // ================= edge update (reads PRE-update xc) =================
        tcast(stream, e_Wq + wo, wtq, 512, 512);
        tcast(stream, e_Wk + wo, wtk, 512, 512);
        tcast(stream, e_Wv + wo, wtv, 512, 512);
        tcast(stream, e_Wo + wo, wto, 512, 512);

        mgemm(stream, lg16, wtq, e_bq + bo_, xc, dst_ids, qe16, NEDGES, 512, 512, 0);
        mgemm(stream, lg16, wtk, nullptr,    xc, src_ids, ke16, NEDGES, 512, 512, 0);
        mgemm(stream, lg16, wtv, nullptr,    xc, src_ids, ve16, NEDGES, 512, 512, 0);

        attend_kernel<<<NEDGES, 256, 0, stream>>>(
            qe16, ke16, ve16, nullptr, lg_src, e_off, e_idx, NEDGES);

        // attn-out + residual, in place over lg16
        mgemm(stream, qe16, wto, e_bo + bo_, lg16, nullptr, lg16, NEDGES, 512, 512, 0);
        ln_kernel<<<(NEDGES + 3) / 4, 256, 0, stream>>>(lg16, e_lg + bo_, e_lb + bo_, NEDGES);

        tcast(stream, e_f1 + f1o, wtf1, 512, 2048);
        tcast(stream, e_f2 + f2o, wtf2, 2048, 512);
        // FFN over edges, 4 chunks of 12500 rows; hidden reuses ve16
        for (int c = 0; c < 4; ++c) {
            unsigned short* y1c = lg16 + (size_t)c * 12500 * DMODEL;
            mgemm(stream, y1c, wtf1, e_fb1 + b1o, nullptr, nullptr, ve16, 12500, 512, 2048, 1);
            mgemm(stream, ve16, wtf2, e_fb2 + bo_, y1c, nullptr, y1c, 12500, 2048, 512, 0);
        }
        ln_kernel<<<(NEDGES + 3) / 4, 256, 0, stream>>>(lg16, e_fg + bo_, e_fb + bo_, NEDGES);

        unsigned short* t = xc; xc = xn; xn = t;
    }

    // final: bf16 -> fp32 d_out (all d_out scratch dead now)
    float* out_f = (float*)d_out;
    cast_b2f_kernel<<<(XSZ + 255) / 256, 256, 0, stream>>>(xc, out_f, XSZ);
    cast_b2f_kernel<<<(LGSZ + 255) / 256, 256, 0, stream>>>(lg16, out_f + XSZ, LGSZ);
}

// Round 5
// 3219.522 us; speedup vs baseline: 3.4942x; 1.0661x over previous
//
#include <hip/hip_runtime.h>
#include <math.h>

#define NNODES 5000
#define NEDGES 50000
#define NELG   200000
#define DMODEL 512
#define NH     8
#define NLAYERS 2

typedef __bf16 bf16x8 __attribute__((ext_vector_type(8)));
typedef float  f32x4  __attribute__((ext_vector_type(4)));

// ---- bf16 helpers (stored as unsigned short) ------------------------------
__device__ __forceinline__ float b2f(unsigned short u) {
    union { unsigned int i; float f; } c;
    c.i = ((unsigned int)u) << 16;
    return c.f;
}
__device__ __forceinline__ unsigned short f2b(float f) {
    union { float f; unsigned int i; } c;
    c.f = f;
    unsigned int i = c.i;
    return (unsigned short)((i + 0x7fffu + ((i >> 16) & 1u)) >> 16);
}

// ---------------------------------------------------------------------------
// MFMA GEMM with section routing:
// C[M,N](bf16) = A[M,K](bf16) @ Bt[N,K](bf16)^T, N split into N/secN sections
// of width secN, each with its own output buffer / bias / add / gather idx.
// Grid: x = M-tiles (padded to %8 for XCD-stable mapping), y = N-tiles.
// LDS chunk-XOR swizzle kills ds_read_b128 bank conflicts while preserving
// the wave-uniform-base + lane*16 constraint of global_load_lds.
// ---------------------------------------------------------------------------
#define BM 128
#define BN 128
#define BK 32

struct GemmDst {
    unsigned short* C0; unsigned short* C1; unsigned short* C2;
    const unsigned short* a0; const unsigned short* a1; const unsigned short* a2;
    const int* x0; const int* x1; const int* x2;
    const float* b0; const float* b1; const float* b2;
};

__global__ __launch_bounds__(256) void mfma_gemm_kernel(
    const unsigned short* __restrict__ A, const unsigned short* __restrict__ Bt,
    GemmDst P, int M, int K, int N, int secN, int relu)
{
    __shared__ __align__(16) unsigned short ldsA[BM * BK];  // 8 KB
    __shared__ __align__(16) unsigned short ldsB[BN * BK];  // 8 KB

    const int rowBase = blockIdx.x * BM;
    if (rowBase >= M) return;                   // grid padding blocks
    const int colBase = blockIdx.y * BN;

    const int tid  = threadIdx.x;
    const int lane = tid & 63;
    const int wave = tid >> 6;
    const int quad = lane >> 4;
    const int l16  = lane & 15;
    const int wm = (wave >> 1) * 64;
    const int wn = (wave & 1) * 64;

    // staging groups: g covers LDS slot g (16 B). row=g>>2, slot=g&3.
    // slot s holds global chunk c = s ^ ((row>>1)&3)  (XOR swizzle)
    const int g0 = tid, g1 = tid + 256;
    const int r0 = g0 >> 2, r1 = g1 >> 2;
    const int c0g = (g0 & 3) ^ ((r0 >> 1) & 3);
    const int c1g = (g1 & 3) ^ ((r1 >> 1) & 3);
    int ra0 = rowBase + r0; if (ra0 > M - 1) ra0 = M - 1;
    int ra1 = rowBase + r1; if (ra1 > M - 1) ra1 = M - 1;
    const unsigned short* gA0 = A + (size_t)ra0 * K + c0g * 8;
    const unsigned short* gA1 = A + (size_t)ra1 * K + c1g * 8;
    const unsigned short* gB0 = Bt + (size_t)(colBase + r0) * K + c0g * 8;
    const unsigned short* gB1 = Bt + (size_t)(colBase + r1) * K + c1g * 8;
    unsigned short* lA0 = ldsA + g0 * 8;
    unsigned short* lA1 = ldsA + g1 * 8;
    unsigned short* lB0 = ldsB + g0 * 8;
    unsigned short* lB1 = ldsB + g1 * 8;

    // fragment-read swizzled chunk offset (elements)
    const int swz = (l16 >> 1) & 3;
    const int ca = (quad ^ swz) * 8;

    const f32x4 zv = {0.f, 0.f, 0.f, 0.f};
    f32x4 acc[4][4];
    #pragma unroll
    for (int i = 0; i < 4; ++i)
        #pragma unroll
        for (int j = 0; j < 4; ++j) acc[i][j] = zv;

    for (int k0 = 0; k0 < K; k0 += BK) {
        __builtin_amdgcn_global_load_lds(
            (const __attribute__((address_space(1))) void*)(gA0 + k0),
            (__attribute__((address_space(3))) void*)lA0, 16, 0, 0);
        __builtin_amdgcn_global_load_lds(
            (const __attribute__((address_space(1))) void*)(gA1 + k0),
            (__attribute__((address_space(3))) void*)lA1, 16, 0, 0);
        __builtin_amdgcn_global_load_lds(
            (const __attribute__((address_space(1))) void*)(gB0 + k0),
            (__attribute__((address_space(3))) void*)lB0, 16, 0, 0);
        __builtin_amdgcn_global_load_lds(
            (const __attribute__((address_space(1))) void*)(gB1 + k0),
            (__attribute__((address_space(3))) void*)lB1, 16, 0, 0);
        __syncthreads();

        bf16x8 af[4], bfr[4];
        #pragma unroll
        for (int i = 0; i < 4; ++i)
            af[i] = *(const bf16x8*)(ldsA + (wm + i * 16 + l16) * BK + ca);
        #pragma unroll
        for (int j = 0; j < 4; ++j)
            bfr[j] = *(const bf16x8*)(ldsB + (wn + j * 16 + l16) * BK + ca);
        #pragma unroll
        for (int i = 0; i < 4; ++i)
            #pragma unroll
            for (int j = 0; j < 4; ++j)
                acc[i][j] = __builtin_amdgcn_mfma_f32_16x16x32_bf16(
                    af[i], bfr[j], acc[i][j], 0, 0, 0);
        __syncthreads();
    }

    // section routing (secN >= 512, multiple of BN, so uniform per block)
    const int sec   = colBase / secN;
    const int cbase = colBase - sec * secN;
    unsigned short*       Cs = (sec == 0) ? P.C0 : ((sec == 1) ? P.C1 : P.C2);
    const unsigned short* ad = (sec == 0) ? P.a0 : ((sec == 1) ? P.a1 : P.a2);
    const int*            gx = (sec == 0) ? P.x0 : ((sec == 1) ? P.x1 : P.x2);
    const float*          bs = (sec == 0) ? P.b0 : ((sec == 1) ? P.b1 : P.b2);

    #pragma unroll
    for (int i = 0; i < 4; ++i) {
        #pragma unroll
        for (int r = 0; r < 4; ++r) {
            const int row = rowBase + wm + i * 16 + quad * 4 + r;
            if (row >= M) continue;
            const int arow = gx ? gx[row] : row;
            const unsigned short* addr = ad ? ad + (size_t)arow * secN : nullptr;
            unsigned short* crow = Cs + (size_t)row * secN;
            #pragma unroll
            for (int j = 0; j < 4; ++j) {
                const int col = cbase + wn + j * 16 + l16;
                float v = acc[i][j][r];
                if (bs) v += bs[col];
                if (addr) v += b2f(addr[col]);
                if (relu) v = fmaxf(v, 0.0f);
                crow[col] = f2b(v);
            }
        }
    }
}

// ---------------------------------------------------------------------------
// W[K][N] fp32 -> Wt[N][K] bf16
// ---------------------------------------------------------------------------
__global__ __launch_bounds__(256) void transpose_cast_kernel(
    const float* __restrict__ W, unsigned short* __restrict__ Wt, int K, int N)
{
    __shared__ float t[32][33];
    const int n0 = blockIdx.x << 5, k0 = blockIdx.y << 5;
    const int tx = threadIdx.x & 31, ty = threadIdx.x >> 5;
    #pragma unroll
    for (int r = 0; r < 32; r += 8)
        t[ty + r][tx] = W[(size_t)(k0 + ty + r) * N + n0 + tx];
    __syncthreads();
    #pragma unroll
    for (int r = 0; r < 32; r += 8)
        Wt[(size_t)(n0 + ty + r) * K + k0 + tx] = f2b(t[tx][ty + r]);
}

// ---------------------------------------------------------------------------
// LayerNorm in place over bf16 rows of width 512. One wave per row.
// ---------------------------------------------------------------------------
__global__ __launch_bounds__(256) void ln_kernel(
    unsigned short* __restrict__ x, const float* __restrict__ g,
    const float* __restrict__ b, int M)
{
    const int row = blockIdx.x * 4 + (threadIdx.x >> 6);
    if (row >= M) return;
    const int lane = threadIdx.x & 63;
    unsigned short* xr = x + (size_t)row * DMODEL;

    float vals[8];
    float s = 0.f, s2 = 0.f;
    #pragma unroll
    for (int i = 0; i < 8; ++i) {
        const float v = b2f(xr[lane + i * 64]);
        vals[i] = v; s += v; s2 += v * v;
    }
    #pragma unroll
    for (int o = 32; o > 0; o >>= 1) {
        s  += __shfl_down(s, o);
        s2 += __shfl_down(s2, o);
    }
    s  = __shfl(s, 0);
    s2 = __shfl(s2, 0);
    const float m = s * (1.0f / DMODEL);
    const float var = s2 * (1.0f / DMODEL) - m * m;
    const float r = rsqrtf(var + 1e-5f);
    #pragma unroll
    for (int i = 0; i < 8; ++i) {
        const int c = lane + i * 64;
        xr[c] = f2b((vals[i] - m) * r * g[c] + b[c]);
    }
}

// ---------------------------------------------------------------------------
// CSR build: histogram -> single-block scan -> scatter
// ---------------------------------------------------------------------------
__global__ __launch_bounds__(256) void hist_kernel(
    const int* __restrict__ dst, int* __restrict__ cnt, int ne)
{
    const int j = blockIdx.x * 256 + threadIdx.x;
    if (j < ne) atomicAdd(&cnt[dst[j]], 1);
}

__global__ __launch_bounds__(1024) void scan_kernel(
    const int* __restrict__ cnt, int* __restrict__ off,
    int* __restrict__ cur, int n)
{
    __shared__ int part[1024];
    const int t = threadIdx.x;
    const int chunk = (n + 1023) >> 10;
    const int lo = t * chunk;
    int hi = lo + chunk; if (hi > n) hi = n;
    int s = 0;
    for (int i = lo; i < hi; ++i) s += cnt[i];
    part[t] = s;
    __syncthreads();
    #pragma unroll
    for (int o = 1; o < 1024; o <<= 1) {
        int v = (t >= o) ? part[t - o] : 0;
        __syncthreads();
        part[t] += v;
        __syncthreads();
    }
    int base = (t == 0) ? 0 : part[t - 1];
    const int total = part[1023];
    for (int i = lo; i < hi; ++i) {
        const int c = cnt[i];
        off[i] = base; cur[i] = base;
        base += c;
    }
    if (t == 1023) off[n] = total;
}

__global__ __launch_bounds__(256) void scatter_kernel(
    const int* __restrict__ dst, int* __restrict__ cur,
    int* __restrict__ idx, int ne)
{
    const int j = blockIdx.x * 256 + threadIdx.x;
    if (j < ne) {
        const int p = atomicAdd(&cur[dst[j]], 1);
        idx[p] = j;
    }
}

// ---------------------------------------------------------------------------
// Fused CSR attention. One block (256 thr) per destination segment.
// q row overwritten with output (each row touched only by its own block).
// ---------------------------------------------------------------------------
__global__ __launch_bounds__(256) void attend_kernel(
    unsigned short* __restrict__ q,
    const unsigned short* __restrict__ k,
    const unsigned short* __restrict__ v,
    const unsigned short* __restrict__ efeat,
    const int* __restrict__ src,
    const int* __restrict__ off, const int* __restrict__ idx,
    int nseg)
{
    const int seg = blockIdx.x;
    if (seg >= nseg) return;
    const int t = threadIdx.x;
    const int lane = t & 63;
    const int c0 = t * 2;
    unsigned short* qrow = q + (size_t)seg * DMODEL;
    const ushort2 q2 = *(const ushort2*)(qrow + c0);
    const float qv0 = b2f(q2.x), qv1 = b2f(q2.y);

    float acc0 = 0.f, acc1 = 0.f, zsum = 0.f;
    const int lo = off[seg], hi = off[seg + 1];
    for (int j = lo; j < hi; ++j) {
        const int e = idx[j];
        const int s = src[e];
        const ushort2 k2 = *(const ushort2*)(k + (size_t)s * DMODEL + c0);
        const ushort2 v2 = *(const ushort2*)(v + (size_t)s * DMODEL + c0);
        float kv0 = b2f(k2.x), kv1 = b2f(k2.y);
        float vv0 = b2f(v2.x), vv1 = b2f(v2.y);
        if (efeat) {
            const ushort2 e2 = *(const ushort2*)(efeat + (size_t)e * DMODEL + c0);
            const float e0 = b2f(e2.x), e1 = b2f(e2.y);
            kv0 += e0; kv1 += e1; vv0 += e0; vv1 += e1;
        }
        float p = kv0 * qv0 + kv1 * qv1;
        #pragma unroll
        for (int o = 16; o > 0; o >>= 1) p += __shfl_down(p, o, 32);
        p = __shfl(p, lane & 32);
        float sc = p * 0.125f;
        sc = fminf(fmaxf(sc, -10.0f), 10.0f);
        sc = __expf(sc);
        zsum += sc;
        acc0 = fmaf(sc, vv0, acc0);
        acc1 = fmaf(sc, vv1, acc1);
    }
    const float rz = 1.0f / zsum;
    ushort2 o2;
    o2.x = f2b(acc0 * rz);
    o2.y = f2b(acc1 * rz);
    *(ushort2*)(qrow + c0) = o2;
}

// ---------------------------------------------------------------------------
__global__ __launch_bounds__(256) void gather_rel_kernel(
    const float* __restrict__ rel, const int* __restrict__ ef,
    unsigned short* __restrict__ lg)
{
    const int idx = blockIdx.x * 256 + threadIdx.x;
    if (idx >= NEDGES * DMODEL) return;
    const int e = idx >> 9;
    const int col = idx & 511;
    lg[idx] = f2b(rel[(size_t)ef[e] * DMODEL + col]);
}

__global__ __launch_bounds__(256) void cast_f2b_kernel(
    const float* __restrict__ in, unsigned short* __restrict__ out, int n)
{
    const int idx = blockIdx.x * 256 + threadIdx.x;
    if (idx < n) out[idx] = f2b(in[idx]);
}

__global__ __launch_bounds__(256) void cast_b2f_kernel(
    const unsigned short* __restrict__ in, float* __restrict__ out, int n)
{
    const int idx = blockIdx.x * 256 + threadIdx.x;
    if (idx < n) out[idx] = b2f(in[idx]);
}

__global__ __launch_bounds__(256) void zero_kernel(float4* __restrict__ p, int n4)
{
    const int idx = blockIdx.x * 256 + threadIdx.x;
    if (idx < n4) p[idx] = make_float4(0.f, 0.f, 0.f, 0.f);
}

// ---------------------------------------------------------------------------
static inline dim3 gemm_grid(int M, int N)
{
    int mt = (M + BM - 1) / BM;
    mt = (mt + 7) & ~7;               // pad so M-tile -> XCD is y-invariant
    return dim3(mt, N / BN);
}

static inline void mgemm(hipStream_t st, const unsigned short* A, const unsigned short* Bt,
                         const float* bias, const unsigned short* add, const int* gidx,
                         unsigned short* C, int M, int K, int N, int relu)
{
    GemmDst P = {C, nullptr, nullptr, add, nullptr, nullptr,
                 gidx, nullptr, nullptr, bias, nullptr, nullptr};
    mfma_gemm_kernel<<<gemm_grid(M, N), 256, 0, st>>>(A, Bt, P, M, K, N, N, relu);
}

// fused QKV: Bt rows [0,512)=Wq, [512,1024)=Wk, [1024,1536)=Wv (contiguous)
static inline void mgemm_qkv(hipStream_t st, const unsigned short* A, const unsigned short* Bt,
                             const float* biasQ,
                             const unsigned short* addQ, const int* gxQ,
                             const unsigned short* addKV, const int* gxKV,
                             unsigned short* Cq, unsigned short* Ck, unsigned short* Cv,
                             int M, int K)
{
    GemmDst P = {Cq, Ck, Cv, addQ, addKV, addKV,
                 gxQ, gxKV, gxKV, biasQ, nullptr, nullptr};
    mfma_gemm_kernel<<<gemm_grid(M, 1536), 256, 0, st>>>(A, Bt, P, M, K, 1536, 512, 0);
}

static inline void tcast(hipStream_t st, const float* W, unsigned short* Wt, int K, int N)
{
    dim3 g(N / 32, K / 32);
    transpose_cast_kernel<<<g, 256, 0, st>>>(W, Wt, K, N);
}
static inline void zero(hipStream_t st, void* p, size_t nfloats)
{
    const int n4 = (int)(nfloats / 4);
    zero_kernel<<<(n4 + 255) / 256, 256, 0, st>>>((float4*)p, n4);
}

extern "C" void kernel_launch(void* const* d_in, const int* in_sizes, int n_in,
                              void* d_out, int out_size, void* d_ws, size_t ws_size,
                              hipStream_t stream)
{
    const float* x_in      = (const float*)d_in[0];
    const int*   edge_feat = (const int*)d_in[1];
    const int*   src_ids   = (const int*)d_in[2];
    const int*   dst_ids   = (const int*)d_in[3];
    const int*   lg_src    = (const int*)d_in[4];
    const int*   lg_dst    = (const int*)d_in[5];
    const float* rel_embed = (const float*)d_in[6];

    const float* n_Wq = (const float*)d_in[7];   const float* n_bq = (const float*)d_in[8];
    const float* n_Wk = (const float*)d_in[9];   const float* n_Wv = (const float*)d_in[10];
    const float* n_Wo = (const float*)d_in[11];  const float* n_bo = (const float*)d_in[12];
    const float* n_lg = (const float*)d_in[13];  const float* n_lb = (const float*)d_in[14];
    const float* n_f1 = (const float*)d_in[15];  const float* n_fb1 = (const float*)d_in[16];
    const float* n_f2 = (const float*)d_in[17];  const float* n_fb2 = (const float*)d_in[18];
    const float* n_fg = (const float*)d_in[19];  const float* n_fb = (const float*)d_in[20];

    const float* e_Wq = (const float*)d_in[21];  const float* e_bq = (const float*)d_in[22];
    const float* e_Wk = (const float*)d_in[23];  const float* e_Wv = (const float*)d_in[24];
    const float* e_Wo = (const float*)d_in[25];  const float* e_bo = (const float*)d_in[26];
    const float* e_lg = (const float*)d_in[27];  const float* e_lb = (const float*)d_in[28];
    const float* e_f1 = (const float*)d_in[29];  const float* e_fb1 = (const float*)d_in[30];
    const float* e_f2 = (const float*)d_in[31];  const float* e_fb2 = (const float*)d_in[32];
    const float* e_fg = (const float*)d_in[33];  const float* e_fb = (const float*)d_in[34];

    const int XSZ  = NNODES * DMODEL;
    const int LGSZ = NEDGES * DMODEL;

    // ---- workspace layout ---------------------------------------------------
    char* ws = (char*)d_ws;
    unsigned short* lg16  = (unsigned short*)(ws);               // 51,200,000 B
    unsigned short* ve16  = (unsigned short*)(ws + 51200000);    // 51,200,000 B
    int* n_off = (int*)(ws + 102400000);
    int* n_cur = (int*)(ws + 102420480);
    int* n_idx = (int*)(ws + 102440960);
    int* e_off = (int*)(ws + 102641664);
    int* e_cur = (int*)(ws + 102842368);
    int* e_idx = (int*)(ws + 103043072);                         // ends 103.84 MB
    unsigned short* xbufA = (unsigned short*)(ws + 110400000);   // 5,120,000 B
    unsigned short* xbufB = (unsigned short*)(ws + 115520000);   // 5,120,000 B

    // ---- d_out scratch (112.64 MB) -----------------------------------------
    char* ob = (char*)d_out;
    unsigned short* qe16 = (unsigned short*)(ob);                // 51.2 MB
    unsigned short* ke16 = (unsigned short*)(ob + 51200000);     // 51.2 MB
    unsigned short* nq16 = (unsigned short*)(ob);
    unsigned short* nk16 = (unsigned short*)(ob + 5120000);
    unsigned short* nv16 = (unsigned short*)(ob + 10240000);
    unsigned short* nhid = (unsigned short*)(ob);                // 20.48 MB
    unsigned short* wtq  = (unsigned short*)(ob + 102400000);    // q|k|v contiguous
    unsigned short* wtk  = (unsigned short*)(ob + 102924288);
    unsigned short* wtv  = (unsigned short*)(ob + 103448576);
    unsigned short* wto  = (unsigned short*)(ob + 103972864);
    unsigned short* wtf1 = (unsigned short*)(ob + 104497152);    // 2 MB
    unsigned short* wtf2 = (unsigned short*)(ob + 106594304);    // 2 MB (ends 108.7 MB)

    // ---- init + CSR build ---------------------------------------------------
    cast_f2b_kernel<<<(XSZ + 255) / 256, 256, 0, stream>>>(x_in, xbufA, XSZ);
    gather_rel_kernel<<<(LGSZ + 255) / 256, 256, 0, stream>>>(rel_embed, edge_feat, lg16);

    zero(stream, n_cur, NNODES);
    zero(stream, e_cur, NEDGES);
    hist_kernel<<<(NEDGES + 255) / 256, 256, 0, stream>>>(dst_ids, n_cur, NEDGES);
    hist_kernel<<<(NELG + 255) / 256, 256, 0, stream>>>(lg_dst, e_cur, NELG);
    scan_kernel<<<1, 1024, 0, stream>>>(n_cur, n_off, n_cur, NNODES);
    scan_kernel<<<1, 1024, 0, stream>>>(e_cur, e_off, e_cur, NEDGES);
    scatter_kernel<<<(NEDGES + 255) / 256, 256, 0, stream>>>(dst_ids, n_cur, n_idx, NEDGES);
    scatter_kernel<<<(NELG + 255) / 256, 256, 0, stream>>>(lg_dst, e_cur, e_idx, NELG);

    unsigned short* xc = xbufA;
    unsigned short* xn = xbufB;

    for (int i = 0; i < NLAYERS; ++i) {
        const size_t wo  = (size_t)i * DMODEL * DMODEL;
        const size_t bo_ = (size_t)i * DMODEL;
        const size_t f1o = (size_t)i * DMODEL * 4 * DMODEL;
        const size_t b1o = (size_t)i * 4 * DMODEL;
        const size_t f2o = (size_t)i * 4 * DMODEL * DMODEL;

        // ================= node update (reads xc, lg16) =================
        tcast(stream, n_Wq + wo, wtq, 512, 512);
        tcast(stream, n_Wk + wo, wtk, 512, 512);
        tcast(stream, n_Wv + wo, wtv, 512, 512);
        tcast(stream, n_Wo + wo, wto, 512, 512);
        tcast(stream, n_f1 + f1o, wtf1, 512, 2048);
        tcast(stream, n_f2 + f2o, wtf2, 2048, 512);

        mgemm_qkv(stream, xc, wtq, n_bq + bo_,
                  nullptr, nullptr, nullptr, nullptr,
                  nq16, nk16, nv16, NNODES, 512);

        attend_kernel<<<NNODES, 256, 0, stream>>>(
            nq16, nk16, nv16, lg16, src_ids, n_off, n_idx, NNODES);

        mgemm(stream, nq16, wto, n_bo + bo_, xc, nullptr, xn, NNODES, 512, 512, 0);
        ln_kernel<<<(NNODES + 3) / 4, 256, 0, stream>>>(xn, n_lg + bo_, n_lb + bo_, NNODES);
        mgemm(stream, xn, wtf1, n_fb1 + b1o, nullptr, nullptr, nhid, NNODES, 512, 2048, 1);
        mgemm(stream, nhid, wtf2, n_fb2 + bo_, xn, nullptr, xn, NNODES, 2048, 512, 0);
        ln_kernel<<<(NNODES + 3) / 4, 256, 0, stream>>>(xn, n_fg + bo_, n_fb + bo_, NNODES);

        // ================= edge update (reads PRE-update xc) =================
        tcast(stream, e_Wq + wo, wtq, 512, 512);
        tcast(stream, e_Wk + wo, wtk, 512, 512);
        tcast(stream, e_Wv + wo, wtv, 512, 512);
        tcast(stream, e_Wo + wo, wto, 512, 512);

        mgemm_qkv(stream, lg16, wtq, e_bq + bo_,
                  xc, dst_ids, xc, src_ids,
                  qe16, ke16, ve16, NEDGES, 512);

        attend_kernel<<<NEDGES, 256, 0, stream>>>(
            qe16, ke16, ve16, nullptr, lg_src, e_off, e_idx, NEDGES);

        mgemm(stream, qe16, wto, e_bo + bo_, lg16, nullptr, lg16, NEDGES, 512, 512, 0);
        ln_kernel<<<(NEDGES + 3) / 4, 256, 0, stream>>>(lg16, e_lg + bo_, e_lb + bo_, NEDGES);

        tcast(stream, e_f1 + f1o, wtf1, 512, 2048);
        tcast(stream, e_f2 + f2o, wtf2, 2048, 512);
        for (int c = 0; c < 4; ++c) {
            unsigned short* y1c = lg16 + (size_t)c * 12500 * DMODEL;
            mgemm(stream, y1c, wtf1, e_fb1 + b1o, nullptr, nullptr, ve16, 12500, 512, 2048, 1);
            mgemm(stream, ve16, wtf2, e_fb2 + bo_, y1c, nullptr, y1c, 12500, 2048, 512, 0);
        }
        ln_kernel<<<(NEDGES + 3) / 4, 256, 0, stream>>>(lg16, e_fg + bo_, e_fb + bo_, NEDGES);

        unsigned short* t = xc; xc = xn; xn = t;
    }

    // final: bf16 -> fp32 d_out (all d_out scratch dead now)
    float* out_f = (float*)d_out;
    cast_b2f_kernel<<<(XSZ + 255) / 256, 256, 0, stream>>>(xc, out_f, XSZ);
    cast_b2f_kernel<<<(LGSZ + 255) / 256, 256, 0, stream>>>(lg16, out_f + XSZ, LGSZ);
}

// Round 6
// 3215.080 us; speedup vs baseline: 3.4990x; 1.0014x over previous
//
#include <hip/hip_runtime.h>
#include <math.h>

#define NNODES 5000
#define NEDGES 50000
#define NELG   200000
#define DMODEL 512
#define NH     8
#define NLAYERS 2

typedef __bf16 bf16x8 __attribute__((ext_vector_type(8)));
typedef float  f32x4  __attribute__((ext_vector_type(4)));
typedef unsigned short us8v __attribute__((ext_vector_type(8)));

// ---- bf16 helpers (stored as unsigned short) ------------------------------
__device__ __forceinline__ float b2f(unsigned short u) {
    union { unsigned int i; float f; } c;
    c.i = ((unsigned int)u) << 16;
    return c.f;
}
__device__ __forceinline__ unsigned short f2b(float f) {
    union { float f; unsigned int i; } c;
    c.f = f;
    unsigned int i = c.i;
    return (unsigned short)((i + 0x7fffu + ((i >> 16) & 1u)) >> 16);
}

// ---------------------------------------------------------------------------
// MFMA GEMM with section routing. Grid: x = N-tiles (FAST — all column
// blocks of an M-tile co-resident => A-tile reuse hits L2/L3 in-window),
// y = M-tiles. LDS chunk-XOR swizzle keeps ds_read_b128 conflict-free.
// ---------------------------------------------------------------------------
#define BM 128
#define BN 128
#define BK 32

struct GemmDst {
    unsigned short* C0; unsigned short* C1; unsigned short* C2;
    const unsigned short* a0; const unsigned short* a1; const unsigned short* a2;
    const int* x0; const int* x1; const int* x2;
    const float* b0; const float* b1; const float* b2;
};

__global__ __launch_bounds__(256) void mfma_gemm_kernel(
    const unsigned short* __restrict__ A, const unsigned short* __restrict__ Bt,
    GemmDst P, int M, int K, int N, int secN, int relu)
{
    __shared__ __align__(16) unsigned short ldsA[BM * BK];  // 8 KB
    __shared__ __align__(16) unsigned short ldsB[BN * BK];  // 8 KB

    const int rowBase = blockIdx.y * BM;
    const int colBase = blockIdx.x * BN;

    const int tid  = threadIdx.x;
    const int lane = tid & 63;
    const int wave = tid >> 6;
    const int quad = lane >> 4;
    const int l16  = lane & 15;
    const int wm = (wave >> 1) * 64;
    const int wn = (wave & 1) * 64;

    // staging: group g -> LDS slot g (16 B). row=g>>2, slot=g&3.
    // slot s holds global chunk c = s ^ ((row>>1)&3)  (XOR swizzle)
    const int g0 = tid, g1 = tid + 256;
    const int r0 = g0 >> 2, r1 = g1 >> 2;
    const int c0g = (g0 & 3) ^ ((r0 >> 1) & 3);
    const int c1g = (g1 & 3) ^ ((r1 >> 1) & 3);
    int ra0 = rowBase + r0; if (ra0 > M - 1) ra0 = M - 1;
    int ra1 = rowBase + r1; if (ra1 > M - 1) ra1 = M - 1;
    const unsigned short* gA0 = A + (size_t)ra0 * K + c0g * 8;
    const unsigned short* gA1 = A + (size_t)ra1 * K + c1g * 8;
    const unsigned short* gB0 = Bt + (size_t)(colBase + r0) * K + c0g * 8;
    const unsigned short* gB1 = Bt + (size_t)(colBase + r1) * K + c1g * 8;
    unsigned short* lA0 = ldsA + g0 * 8;
    unsigned short* lA1 = ldsA + g1 * 8;
    unsigned short* lB0 = ldsB + g0 * 8;
    unsigned short* lB1 = ldsB + g1 * 8;

    const int swz = (l16 >> 1) & 3;
    const int ca = (quad ^ swz) * 8;

    const f32x4 zv = {0.f, 0.f, 0.f, 0.f};
    f32x4 acc[4][4];
    #pragma unroll
    for (int i = 0; i < 4; ++i)
        #pragma unroll
        for (int j = 0; j < 4; ++j) acc[i][j] = zv;

    for (int k0 = 0; k0 < K; k0 += BK) {
        __builtin_amdgcn_global_load_lds(
            (const __attribute__((address_space(1))) void*)(gA0 + k0),
            (__attribute__((address_space(3))) void*)lA0, 16, 0, 0);
        __builtin_amdgcn_global_load_lds(
            (const __attribute__((address_space(1))) void*)(gA1 + k0),
            (__attribute__((address_space(3))) void*)lA1, 16, 0, 0);
        __builtin_amdgcn_global_load_lds(
            (const __attribute__((address_space(1))) void*)(gB0 + k0),
            (__attribute__((address_space(3))) void*)lB0, 16, 0, 0);
        __builtin_amdgcn_global_load_lds(
            (const __attribute__((address_space(1))) void*)(gB1 + k0),
            (__attribute__((address_space(3))) void*)lB1, 16, 0, 0);
        __syncthreads();

        bf16x8 af[4], bfr[4];
        #pragma unroll
        for (int i = 0; i < 4; ++i)
            af[i] = *(const bf16x8*)(ldsA + (wm + i * 16 + l16) * BK + ca);
        #pragma unroll
        for (int j = 0; j < 4; ++j)
            bfr[j] = *(const bf16x8*)(ldsB + (wn + j * 16 + l16) * BK + ca);
        #pragma unroll
        for (int i = 0; i < 4; ++i)
            #pragma unroll
            for (int j = 0; j < 4; ++j)
                acc[i][j] = __builtin_amdgcn_mfma_f32_16x16x32_bf16(
                    af[i], bfr[j], acc[i][j], 0, 0, 0);
        __syncthreads();
    }

    const int sec   = colBase / secN;
    const int cbase = colBase - sec * secN;
    unsigned short*       Cs = (sec == 0) ? P.C0 : ((sec == 1) ? P.C1 : P.C2);
    const unsigned short* ad = (sec == 0) ? P.a0 : ((sec == 1) ? P.a1 : P.a2);
    const int*            gx = (sec == 0) ? P.x0 : ((sec == 1) ? P.x1 : P.x2);
    const float*          bs = (sec == 0) ? P.b0 : ((sec == 1) ? P.b1 : P.b2);

    #pragma unroll
    for (int i = 0; i < 4; ++i) {
        #pragma unroll
        for (int r = 0; r < 4; ++r) {
            const int row = rowBase + wm + i * 16 + quad * 4 + r;
            if (row >= M) continue;
            const int arow = gx ? gx[row] : row;
            const unsigned short* addr = ad ? ad + (size_t)arow * secN : nullptr;
            unsigned short* crow = Cs + (size_t)row * secN;
            #pragma unroll
            for (int j = 0; j < 4; ++j) {
                const int col = cbase + wn + j * 16 + l16;
                float v = acc[i][j][r];
                if (bs) v += bs[col];
                if (addr) v += b2f(addr[col]);
                if (relu) v = fmaxf(v, 0.0f);
                crow[col] = f2b(v);
            }
        }
    }
}

// ---------------------------------------------------------------------------
// W[K][N] fp32 -> Wt[N][K] bf16
// ---------------------------------------------------------------------------
__global__ __launch_bounds__(256) void transpose_cast_kernel(
    const float* __restrict__ W, unsigned short* __restrict__ Wt, int K, int N)
{
    __shared__ float t[32][33];
    const int n0 = blockIdx.x << 5, k0 = blockIdx.y << 5;
    const int tx = threadIdx.x & 31, ty = threadIdx.x >> 5;
    #pragma unroll
    for (int r = 0; r < 32; r += 8)
        t[ty + r][tx] = W[(size_t)(k0 + ty + r) * N + n0 + tx];
    __syncthreads();
    #pragma unroll
    for (int r = 0; r < 32; r += 8)
        Wt[(size_t)(n0 + ty + r) * K + k0 + tx] = f2b(t[tx][ty + r]);
}

// ---------------------------------------------------------------------------
// LayerNorm in place over bf16 rows of width 512. One wave per row.
// ---------------------------------------------------------------------------
__global__ __launch_bounds__(256) void ln_kernel(
    unsigned short* __restrict__ x, const float* __restrict__ g,
    const float* __restrict__ b, int M)
{
    const int row = blockIdx.x * 4 + (threadIdx.x >> 6);
    if (row >= M) return;
    const int lane = threadIdx.x & 63;
    unsigned short* xr = x + (size_t)row * DMODEL;

    float vals[8];
    float s = 0.f, s2 = 0.f;
    #pragma unroll
    for (int i = 0; i < 8; ++i) {
        const float v = b2f(xr[lane + i * 64]);
        vals[i] = v; s += v; s2 += v * v;
    }
    #pragma unroll
    for (int o = 32; o > 0; o >>= 1) {
        s  += __shfl_down(s, o);
        s2 += __shfl_down(s2, o);
    }
    s  = __shfl(s, 0);
    s2 = __shfl(s2, 0);
    const float m = s * (1.0f / DMODEL);
    const float var = s2 * (1.0f / DMODEL) - m * m;
    const float r = rsqrtf(var + 1e-5f);
    #pragma unroll
    for (int i = 0; i < 8; ++i) {
        const int c = lane + i * 64;
        xr[c] = f2b((vals[i] - m) * r * g[c] + b[c]);
    }
}

// ---------------------------------------------------------------------------
// CSR build: histogram -> single-block scan -> scatter
// ---------------------------------------------------------------------------
__global__ __launch_bounds__(256) void hist_kernel(
    const int* __restrict__ dst, int* __restrict__ cnt, int ne)
{
    const int j = blockIdx.x * 256 + threadIdx.x;
    if (j < ne) atomicAdd(&cnt[dst[j]], 1);
}

__global__ __launch_bounds__(1024) void scan_kernel(
    const int* __restrict__ cnt, int* __restrict__ off,
    int* __restrict__ cur, int n)
{
    __shared__ int part[1024];
    const int t = threadIdx.x;
    const int chunk = (n + 1023) >> 10;
    const int lo = t * chunk;
    int hi = lo + chunk; if (hi > n) hi = n;
    int s = 0;
    for (int i = lo; i < hi; ++i) s += cnt[i];
    part[t] = s;
    __syncthreads();
    #pragma unroll
    for (int o = 1; o < 1024; o <<= 1) {
        int v = (t >= o) ? part[t - o] : 0;
        __syncthreads();
        part[t] += v;
        __syncthreads();
    }
    int base = (t == 0) ? 0 : part[t - 1];
    const int total = part[1023];
    for (int i = lo; i < hi; ++i) {
        const int c = cnt[i];
        off[i] = base; cur[i] = base;
        base += c;
    }
    if (t == 1023) off[n] = total;
}

__global__ __launch_bounds__(256) void scatter_kernel(
    const int* __restrict__ dst, int* __restrict__ cur,
    int* __restrict__ idx, int ne)
{
    const int j = blockIdx.x * 256 + threadIdx.x;
    if (j < ne) {
        const int p = atomicAdd(&cur[dst[j]], 1);
        idx[p] = j;
    }
}

// ---------------------------------------------------------------------------
// Fused CSR attention, wave-parallel over incident edges.
// One block per destination segment; 4 waves each take edges j = lo+wave,
// step 4. Lane covers 8 contiguous cols (ushort8 = 16 B loads). Head = 8
// lanes; score reduced with 3 xor-shuffles. Partials combined through LDS.
// q row overwritten with output (only this block touches it).
// ---------------------------------------------------------------------------
__global__ __launch_bounds__(256) void attend_kernel(
    unsigned short* __restrict__ q,
    const unsigned short* __restrict__ k,
    const unsigned short* __restrict__ v,
    const unsigned short* __restrict__ efeat,
    const int* __restrict__ src,
    const int* __restrict__ off, const int* __restrict__ idx,
    int nseg)
{
    __shared__ float accS[4][DMODEL];   // 8 KB
    __shared__ float zS[4][NH];

    const int seg = blockIdx.x;
    if (seg >= nseg) return;
    const int t = threadIdx.x;
    const int wave = t >> 6, lane = t & 63;
    const int c8 = lane * 8;
    unsigned short* qrow = q + (size_t)seg * DMODEL;

    const us8v q8 = *(const us8v*)(qrow + c8);
    float qv[8];
    #pragma unroll
    for (int j = 0; j < 8; ++j) qv[j] = b2f(q8[j]);

    float acc[8] = {0.f, 0.f, 0.f, 0.f, 0.f, 0.f, 0.f, 0.f};
    float zsum = 0.f;
    const int lo = off[seg], hi = off[seg + 1];
    for (int jj = lo + wave; jj < hi; jj += 4) {
        const int e = idx[jj];
        const int s = src[e];
        const us8v k8 = *(const us8v*)(k + (size_t)s * DMODEL + c8);
        const us8v v8 = *(const us8v*)(v + (size_t)s * DMODEL + c8);
        float p = 0.f;
        float vv[8];
        if (efeat) {
            const us8v e8 = *(const us8v*)(efeat + (size_t)e * DMODEL + c8);
            #pragma unroll
            for (int j = 0; j < 8; ++j) {
                const float ef = b2f(e8[j]);
                p = fmaf(b2f(k8[j]) + ef, qv[j], p);
                vv[j] = b2f(v8[j]) + ef;
            }
        } else {
            #pragma unroll
            for (int j = 0; j < 8; ++j) {
                p = fmaf(b2f(k8[j]), qv[j], p);
                vv[j] = b2f(v8[j]);
            }
        }
        p += __shfl_xor(p, 1);
        p += __shfl_xor(p, 2);
        p += __shfl_xor(p, 4);
        float sc = p * 0.125f;                    // 1/sqrt(64)
        sc = fminf(fmaxf(sc, -10.0f), 10.0f);
        sc = __expf(sc);
        zsum += sc;
        #pragma unroll
        for (int j = 0; j < 8; ++j) acc[j] = fmaf(sc, vv[j], acc[j]);
    }

    #pragma unroll
    for (int j = 0; j < 8; ++j) accS[wave][c8 + j] = acc[j];
    if ((lane & 7) == 0) zS[wave][lane >> 3] = zsum;
    __syncthreads();

    const int c0 = t * 2;
    const int h = c0 >> 6;
    const float a0 = accS[0][c0] + accS[1][c0] + accS[2][c0] + accS[3][c0];
    const float a1 = accS[0][c0 + 1] + accS[1][c0 + 1] + accS[2][c0 + 1] + accS[3][c0 + 1];
    const float z  = zS[0][h] + zS[1][h] + zS[2][h] + zS[3][h];
    const float rz = 1.0f / z;
    ushort2 o2;
    o2.x = f2b(a0 * rz);
    o2.y = f2b(a1 * rz);
    *(ushort2*)(qrow + c0) = o2;
}

// ---------------------------------------------------------------------------
__global__ __launch_bounds__(256) void gather_rel_kernel(
    const float* __restrict__ rel, const int* __restrict__ ef,
    unsigned short* __restrict__ lg)
{
    const int idx = blockIdx.x * 256 + threadIdx.x;
    if (idx >= NEDGES * DMODEL) return;
    const int e = idx >> 9;
    const int col = idx & 511;
    lg[idx] = f2b(rel[(size_t)ef[e] * DMODEL + col]);
}

__global__ __launch_bounds__(256) void cast_f2b_kernel(
    const float* __restrict__ in, unsigned short* __restrict__ out, int n)
{
    const int idx = blockIdx.x * 256 + threadIdx.x;
    if (idx < n) out[idx] = f2b(in[idx]);
}

__global__ __launch_bounds__(256) void cast_b2f_kernel(
    const unsigned short* __restrict__ in, float* __restrict__ out, int n)
{
    const int idx = blockIdx.x * 256 + threadIdx.x;
    if (idx < n) out[idx] = b2f(in[idx]);
}

__global__ __launch_bounds__(256) void zero_kernel(float4* __restrict__ p, int n4)
{
    const int idx = blockIdx.x * 256 + threadIdx.x;
    if (idx < n4) p[idx] = make_float4(0.f, 0.f, 0.f, 0.f);
}

// ---------------------------------------------------------------------------
static inline dim3 gemm_grid(int M, int N)
{
    return dim3(N / BN, (M + BM - 1) / BM);   // N-tiles FAST
}

static inline void mgemm(hipStream_t st, const unsigned short* A, const unsigned short* Bt,
                         const float* bias, const unsigned short* add, const int* gidx,
                         unsigned short* C, int M, int K, int N, int relu)
{
    GemmDst P = {C, nullptr, nullptr, add, nullptr, nullptr,
                 gidx, nullptr, nullptr, bias, nullptr, nullptr};
    mfma_gemm_kernel<<<gemm_grid(M, N), 256, 0, st>>>(A, Bt, P, M, K, N, N, relu);
}

static inline void mgemm_qkv(hipStream_t st, const unsigned short* A, const unsigned short* Bt,
                             const float* biasQ,
                             const unsigned short* addQ, const int* gxQ,
                             const unsigned short* addKV, const int* gxKV,
                             unsigned short* Cq, unsigned short* Ck, unsigned short* Cv,
                             int M, int K)
{
    GemmDst P = {Cq, Ck, Cv, addQ, addKV, addKV,
                 gxQ, gxKV, gxKV, biasQ, nullptr, nullptr};
    mfma_gemm_kernel<<<gemm_grid(M, 1536), 256, 0, st>>>(A, Bt, P, M, K, 1536, 512, 0);
}

static inline void tcast(hipStream_t st, const float* W, unsigned short* Wt, int K, int N)
{
    dim3 g(N / 32, K / 32);
    transpose_cast_kernel<<<g, 256, 0, st>>>(W, Wt, K, N);
}
static inline void zero(hipStream_t st, void* p, size_t nfloats)
{
    const int n4 = (int)(nfloats / 4);
    zero_kernel<<<(n4 + 255) / 256, 256, 0, st>>>((float4*)p, n4);
}

extern "C" void kernel_launch(void* const* d_in, const int* in_sizes, int n_in,
                              void* d_out, int out_size, void* d_ws, size_t ws_size,
                              hipStream_t stream)
{
    const float* x_in      = (const float*)d_in[0];
    const int*   edge_feat = (const int*)d_in[1];
    const int*   src_ids   = (const int*)d_in[2];
    const int*   dst_ids   = (const int*)d_in[3];
    const int*   lg_src    = (const int*)d_in[4];
    const int*   lg_dst    = (const int*)d_in[5];
    const float* rel_embed = (const float*)d_in[6];

    const float* n_Wq = (const float*)d_in[7];   const float* n_bq = (const float*)d_in[8];
    const float* n_Wk = (const float*)d_in[9];   const float* n_Wv = (const float*)d_in[10];
    const float* n_Wo = (const float*)d_in[11];  const float* n_bo = (const float*)d_in[12];
    const float* n_lg = (const float*)d_in[13];  const float* n_lb = (const float*)d_in[14];
    const float* n_f1 = (const float*)d_in[15];  const float* n_fb1 = (const float*)d_in[16];
    const float* n_f2 = (const float*)d_in[17];  const float* n_fb2 = (const float*)d_in[18];
    const float* n_fg = (const float*)d_in[19];  const float* n_fb = (const float*)d_in[20];

    const float* e_Wq = (const float*)d_in[21];  const float* e_bq = (const float*)d_in[22];
    const float* e_Wk = (const float*)d_in[23];  const float* e_Wv = (const float*)d_in[24];
    const float* e_Wo = (const float*)d_in[25];  const float* e_bo = (const float*)d_in[26];
    const float* e_lg = (const float*)d_in[27];  const float* e_lb = (const float*)d_in[28];
    const float* e_f1 = (const float*)d_in[29];  const float* e_fb1 = (const float*)d_in[30];
    const float* e_f2 = (const float*)d_in[31];  const float* e_fb2 = (const float*)d_in[32];
    const float* e_fg = (const float*)d_in[33];  const float* e_fb = (const float*)d_in[34];

    const int XSZ  = NNODES * DMODEL;
    const int LGSZ = NEDGES * DMODEL;

    // ---- workspace layout ---------------------------------------------------
    char* ws = (char*)d_ws;
    unsigned short* lg16  = (unsigned short*)(ws);               // 51,200,000 B
    unsigned short* ve16  = (unsigned short*)(ws + 51200000);    // 51,200,000 B
    int* n_off = (int*)(ws + 102400000);
    int* n_cur = (int*)(ws + 102420480);
    int* n_idx = (int*)(ws + 102440960);
    int* e_off = (int*)(ws + 102641664);
    int* e_cur = (int*)(ws + 102842368);
    int* e_idx = (int*)(ws + 103043072);                         // ends 103.84 MB
    unsigned short* xbufA = (unsigned short*)(ws + 110400000);   // 5,120,000 B
    unsigned short* xbufB = (unsigned short*)(ws + 115520000);   // 5,120,000 B

    // ---- d_out scratch (112.64 MB) -----------------------------------------
    char* ob = (char*)d_out;
    unsigned short* qe16 = (unsigned short*)(ob);                // 51.2 MB
    unsigned short* ke16 = (unsigned short*)(ob + 51200000);     // 51.2 MB
    unsigned short* nq16 = (unsigned short*)(ob);
    unsigned short* nk16 = (unsigned short*)(ob + 5120000);
    unsigned short* nv16 = (unsigned short*)(ob + 10240000);
    unsigned short* nhid = (unsigned short*)(ob);                // 20.48 MB
    unsigned short* wtq  = (unsigned short*)(ob + 102400000);    // q|k|v contiguous
    unsigned short* wtk  = (unsigned short*)(ob + 102924288);
    unsigned short* wtv  = (unsigned short*)(ob + 103448576);
    unsigned short* wto  = (unsigned short*)(ob + 103972864);
    unsigned short* wtf1 = (unsigned short*)(ob + 104497152);    // 2 MB
    unsigned short* wtf2 = (unsigned short*)(ob + 106594304);    // 2 MB (ends 108.7 MB)

    // ---- init + CSR build ---------------------------------------------------
    cast_f2b_kernel<<<(XSZ + 255) / 256, 256, 0, stream>>>(x_in, xbufA, XSZ);
    gather_rel_kernel<<<(LGSZ + 255) / 256, 256, 0, stream>>>(rel_embed, edge_feat, lg16);

    zero(stream, n_cur, NNODES);
    zero(stream, e_cur, NEDGES);
    hist_kernel<<<(NEDGES + 255) / 256, 256, 0, stream>>>(dst_ids, n_cur, NEDGES);
    hist_kernel<<<(NELG + 255) / 256, 256, 0, stream>>>(lg_dst, e_cur, NELG);
    scan_kernel<<<1, 1024, 0, stream>>>(n_cur, n_off, n_cur, NNODES);
    scan_kernel<<<1, 1024, 0, stream>>>(e_cur, e_off, e_cur, NEDGES);
    scatter_kernel<<<(NEDGES + 255) / 256, 256, 0, stream>>>(dst_ids, n_cur, n_idx, NEDGES);
    scatter_kernel<<<(NELG + 255) / 256, 256, 0, stream>>>(lg_dst, e_cur, e_idx, NELG);

    unsigned short* xc = xbufA;
    unsigned short* xn = xbufB;

    for (int i = 0; i < NLAYERS; ++i) {
        const size_t wo  = (size_t)i * DMODEL * DMODEL;
        const size_t bo_ = (size_t)i * DMODEL;
        const size_t f1o = (size_t)i * DMODEL * 4 * DMODEL;
        const size_t b1o = (size_t)i * 4 * DMODEL;
        const size_t f2o = (size_t)i * 4 * DMODEL * DMODEL;

        // ================= node update (reads xc, lg16) =================
        tcast(stream, n_Wq + wo, wtq, 512, 512);
        tcast(stream, n_Wk + wo, wtk, 512, 512);
        tcast(stream, n_Wv + wo, wtv, 512, 512);
        tcast(stream, n_Wo + wo, wto, 512, 512);
        tcast(stream, n_f1 + f1o, wtf1, 512, 2048);
        tcast(stream, n_f2 + f2o, wtf2, 2048, 512);

        mgemm_qkv(stream, xc, wtq, n_bq + bo_,
                  nullptr, nullptr, nullptr, nullptr,
                  nq16, nk16, nv16, NNODES, 512);

        attend_kernel<<<NNODES, 256, 0, stream>>>(
            nq16, nk16, nv16, lg16, src_ids, n_off, n_idx, NNODES);

        mgemm(stream, nq16, wto, n_bo + bo_, xc, nullptr, xn, NNODES, 512, 512, 0);
        ln_kernel<<<(NNODES + 3) / 4, 256, 0, stream>>>(xn, n_lg + bo_, n_lb + bo_, NNODES);
        mgemm(stream, xn, wtf1, n_fb1 + b1o, nullptr, nullptr, nhid, NNODES, 512, 2048, 1);
        mgemm(stream, nhid, wtf2, n_fb2 + bo_, xn, nullptr, xn, NNODES, 2048, 512, 0);
        ln_kernel<<<(NNODES + 3) / 4, 256, 0, stream>>>(xn, n_fg + bo_, n_fb + bo_, NNODES);

        // ================= edge update (reads PRE-update xc) =================
        tcast(stream, e_Wq + wo, wtq, 512, 512);
        tcast(stream, e_Wk + wo, wtk, 512, 512);
        tcast(stream, e_Wv + wo, wtv, 512, 512);
        tcast(stream, e_Wo + wo, wto, 512, 512);

        mgemm_qkv(stream, lg16, wtq, e_bq + bo_,
                  xc, dst_ids, xc, src_ids,
                  qe16, ke16, ve16, NEDGES, 512);

        attend_kernel<<<NEDGES, 256, 0, stream>>>(
            qe16, ke16, ve16, nullptr, lg_src, e_off, e_idx, NEDGES);

        mgemm(stream, qe16, wto, e_bo + bo_, lg16, nullptr, lg16, NEDGES, 512, 512, 0);
        ln_kernel<<<(NEDGES + 3) / 4, 256, 0, stream>>>(lg16, e_lg + bo_, e_lb + bo_, NEDGES);

        tcast(stream, e_f1 + f1o, wtf1, 512, 2048);
        tcast(stream, e_f2 + f2o, wtf2, 2048, 512);
        for (int c = 0; c < 4; ++c) {
            unsigned short* y1c = lg16 + (size_t)c * 12500 * DMODEL;
            mgemm(stream, y1c, wtf1, e_fb1 + b1o, nullptr, nullptr, ve16, 12500, 512, 2048, 1);
            mgemm(stream, ve16, wtf2, e_fb2 + bo_, y1c, nullptr, y1c, 12500, 2048, 512, 0);
        }
        ln_kernel<<<(NEDGES + 3) / 4, 256, 0, stream>>>(lg16, e_fg + bo_, e_fb + bo_, NEDGES);

        unsigned short* t = xc; xc = xn; xn = t;
    }

    // final: bf16 -> fp32 d_out (all d_out scratch dead now)
    float* out_f = (float*)d_out;
    cast_b2f_kernel<<<(XSZ + 255) / 256, 256, 0, stream>>>(xc, out_f, XSZ);
    cast_b2f_kernel<<<(LGSZ + 255) / 256, 256, 0, stream>>>(lg16, out_f + XSZ, LGSZ);
}